// Round 22
// baseline (788.116 us; speedup 1.0000x reference)
//
#include <hip/hip_runtime.h>
#include <math.h>

#define NHH 48
#define NNN 384
#define NP  18432   // NHH*NNN
#define NEC 1024
#define MB1 (1024*1024)

#define BM 128
#define BN 128
#define BK 32
#define KPAD 40     // padded bf16 elems per LDS row

typedef __attribute__((ext_vector_type(8))) short short8v;   // 8 bf16 (4 VGPR)
typedef __attribute__((ext_vector_type(4))) float f32x4;     // MFMA acc

__device__ __forceinline__ unsigned short f2bf(float x) {
  unsigned int u = __float_as_uint(x);
  u += 0x7fffu + ((u >> 16) & 1u);   // RNE
  return (unsigned short)(u >> 16);
}
__device__ __forceinline__ float bf2f(unsigned short b) {
  return __uint_as_float(((unsigned)b) << 16);
}
__device__ __forceinline__ void nt_store8(unsigned x, unsigned y, void* p) {
  unsigned long long v = (unsigned long long)x | ((unsigned long long)y << 32);
  __builtin_nontemporal_store(v, (unsigned long long*)p);
}

// ---------------------------------------------------------------------------
// Weight pre-convert: f32 -> bf16 transposed [N][outK], k in [koff, koff+outK).
// ---------------------------------------------------------------------------
__global__ __launch_bounds__(256) void convw_k(const float* __restrict__ in,
    unsigned short* __restrict__ out, int inK, int outK, int N, int blocked, int koff)
{
  __shared__ float t[64][65];
  int kb = blockIdx.x * 64, nb = blockIdx.y * 64;
  const float* src; size_t stride;
  if (blocked) { src = in + (size_t)(nb >> 6) * inK * 64; stride = 64; }
  else         { src = in + nb; stride = N; }
  for (int i = threadIdx.x; i < 64 * 64; i += 256) {
    int k = i >> 6, d = i & 63;
    t[d][k] = src[(size_t)(kb + koff + k) * stride + d];
  }
  __syncthreads();
  for (int i = threadIdx.x; i < 64 * 64; i += 256) {
    int d = i >> 6, k = i & 63;
    out[(size_t)(nb + d) * outK + kb + k] = f2bf(t[d][k]);
  }
}

// 14 same-shape [1024][1024] conversions in one launch (z = job)
struct CJobs {
  const float* src[14];
  unsigned short* dst[14];
  int inK[14];
  int koff[14];
  int blocked[14];
};
__global__ __launch_bounds__(256) void convjobs_k(CJobs J)
{
  __shared__ float t[64][65];
  int z = blockIdx.z;
  const float* in = J.src[z];
  unsigned short* out = J.dst[z];
  int inK = J.inK[z], koff = J.koff[z], blocked = J.blocked[z];
  int kb = blockIdx.x * 64, nb = blockIdx.y * 64;
  const float* src; size_t stride;
  if (blocked) { src = in + (size_t)(nb >> 6) * inK * 64; stride = 64; }
  else         { src = in + nb; stride = NEC; }
  for (int i = threadIdx.x; i < 64 * 64; i += 256) {
    int k = i >> 6, d = i & 63;
    t[d][k] = src[(size_t)(kb + koff + k) * stride + d];
  }
  __syncthreads();
  for (int i = threadIdx.x; i < 64 * 64; i += 256) {
    int d = i >> 6, k = i & 63;
    out[(size_t)(nb + d) * NEC + kb + k] = f2bf(t[d][k]);
  }
}

// elementwise f32 -> bf16 (n multiple of 4)
__global__ __launch_bounds__(256) void cvt_k(const float* __restrict__ in,
    unsigned short* __restrict__ out, int n)
{
  int i = (blockIdx.x * 256 + threadIdx.x) * 4;
  if (i < n) {
    float4 v = *(const float4*)(in + i);
    unsigned lo = (unsigned)f2bf(v.x) | ((unsigned)f2bf(v.y) << 16);
    unsigned hi = (unsigned)f2bf(v.z) | ((unsigned)f2bf(v.w) << 16);
    nt_store8(lo, hi, out + i);
  }
}

// b3 sums for all four heads in one launch (y = head)
struct Ptr4 { const float* s[4]; float* d[4]; };
__global__ __launch_bounds__(256) void b3sum4_k(Ptr4 P)
{
  int r = blockIdx.x * 256 + threadIdx.x;
  const float* b3 = P.s[blockIdx.y];
  float* out = P.d[blockIdx.y];
  if (r < NEC) {
    float s = 0.f;
#pragma unroll
    for (int c = 0; c < 16; ++c) s += b3[c * NEC + r];
    out[r] = s;
  }
}

// bias4[j] = b_{j>>10}[j&1023]
__global__ __launch_bounds__(256) void biascat4_k(const float* __restrict__ b0,
    const float* __restrict__ b1, const float* __restrict__ b2,
    const float* __restrict__ b3, float* __restrict__ out)
{
  int j = blockIdx.x * 256 + threadIdx.x;
  if (j < 4096) {
    int g = j >> 10, c = j & 1023;
    const float* b = g == 0 ? b0 : (g == 1 ? b1 : (g == 2 ? b2 : b3));
    out[j] = b[c];
  }
}

// ---------------------------------------------------------------------------
// gemm_db: 256 thr / 4 waves / 64x64-per-wave bf16 GEMM, double-buffered LDS
// (ONE barrier per K-step), 2-deep register prefetch. A [M][lda], B [N][ldb].
// Split-K via blockIdx.z (Ks multiple of 64, exact cover).
// All write-once epilogue stores are NON-TEMPORAL (evict-first: keeps the
// reused A/B panels resident in L2/L3 -- the A-resweep then hits cache).
// swz=1: bx-inner bijective XCD remap; grid (gx,144,1).
// swz=2: 3D split-K XCD remap; grid (8, gy, gz), gy*gz % 8 == 0.
// swz=3: phase-grouped remap, grid (gx,144), gx in {16,32}: gx/8 phases.
// MODE 0: C = maybe_relu(acc + bias)
// MODE 1: part[grow*8+bx] = sum_j relu(acc+bias)*x1[j]
// MODE 5: part[(z*M+grow)*N + j] = acc
// MODE 6: fused4 epilogue (N=4096): t=acc+bias[gcol]; group (gcol>>10) routed
//         to FOUR contiguous [M][1024] bf16 buffers at Cv + grp*M*1024;
//         group3 -> relu(x1[col]*t).
// MODE 7: merged output (grid (16,144), swz=3): bx<8 -> {A,B,bias,colofs=0};
//         bx>=8 -> {A=(ushort*)x1 lda 1024 (contig Vg3), B=(ushort*)x2
//         ldb 1024, bias=part, colofs=1024}. Row-remapped store, skip diag.
// ---------------------------------------------------------------------------
template<int MODE, int CBF16>
__global__ __launch_bounds__(256) void gemm_db(
    const unsigned short* __restrict__ A, int lda,
    const unsigned short* __restrict__ B, int ldb,
    void* __restrict__ Cv, int M, int N, int K, int Ks,
    const float* __restrict__ bias, int do_relu,
    const float* __restrict__ x1, const float* __restrict__ x2,
    float* __restrict__ part, int colofs, int swz)
{
  __shared__ unsigned short As[2][BM * KPAD];
  __shared__ unsigned short Bs[2][BN * KPAD];
  __shared__ float red2[BM][2];

  const int tid  = threadIdx.x;
  const int lane = tid & 63;
  const int wave = tid >> 6;
  const int wr = wave >> 1, wc = wave & 1;
  const int lm = lane & 15;
  const int kg = lane >> 4;

  int bx = blockIdx.x, by = blockIdx.y;
  int bz = blockIdx.z;
  if (swz == 1) {                   // grid (gx,144): bx-inner bijective remap
    int gx = gridDim.x;
    int L = by * gx + bx;
    int r = L & 7, q = L >> 3;      // r = XCD class
    bx = q % gx;
    by = r + 8 * (q / gx);
  } else if (swz == 2) {            // grid (8, gy, gz), gy*gz % 8 == 0
    int gy = gridDim.y;
    int ntile = gy * gridDim.z;
    int L = (bz * gy + by) * 8 + bx;
    int r = L & 7, q = L >> 3;
    int tpx = ntile >> 3;
    int tile = r * tpx + (q >> 3);
    bx = q & 7;
    bz = tile / gy;
    by = tile - bz * gy;
  } else if (swz == 3) {            // grid (gx,144): (gx/8) phases x 8 bx
    int gx = gridDim.x;
    int L = by * gx + bx;
    int p = L / 1152, rem = L - p * 1152;
    int r = rem & 7, q = rem >> 3;  // q in 0..143
    bx = p * 8 + (q & 7);
    by = r + 8 * (q >> 3);
  }

  // per-block operand selection (MODE 7 routes by bx group)
  const unsigned short* Ause = A; int ldause = lda;
  const unsigned short* Buse = B; int ldbuse = ldb;
  const float* biasUse = bias;    int cofs = colofs;
  int bxl = bx;
  if constexpr (MODE == 7) {
    if (bx >= 8) {
      Ause = (const unsigned short*)x1; ldause = 1024;   // contiguous Vg3
      Buse = (const unsigned short*)x2; ldbuse = 1024;
      biasUse = part; cofs = 1024;
    }
    bxl = bx & 7;
  }
  const int m0 = by * BM, n0 = bxl * BN;
  const int kbeg = bz * Ks;
  const int kend = min(K, kbeg + Ks);
  const int nt = (kend - kbeg) / BK;   // even by construction

  f32x4 acc[4][4];
#pragma unroll
  for (int i = 0; i < 4; ++i)
#pragma unroll
    for (int j = 0; j < 4; ++j)
      acc[i][j] = (f32x4){0.f, 0.f, 0.f, 0.f};

  const int sr = tid >> 1;
  const int sc = (tid & 1) * 16;
  const unsigned short* aP = Ause + (size_t)(m0 + sr) * ldause + sc;
  const unsigned short* bP = Buse + (size_t)(n0 + sr) * ldbuse + sc;
  const int wofs = sr * KPAD + sc;

  uint4 ra0, ra1, rb0, rb1;   // slot R (even tiles)
  uint4 sa0, sa1, sb0, sb1;   // slot S (odd tiles)

  auto fetchR = [&](int k0) {
    ra0 = *(const uint4*)(aP + k0); ra1 = *(const uint4*)(aP + k0 + 8);
    rb0 = *(const uint4*)(bP + k0); rb1 = *(const uint4*)(bP + k0 + 8);
  };
  auto fetchS = [&](int k0) {
    sa0 = *(const uint4*)(aP + k0); sa1 = *(const uint4*)(aP + k0 + 8);
    sb0 = *(const uint4*)(bP + k0); sb1 = *(const uint4*)(bP + k0 + 8);
  };
  auto writeR = [&](int buf) {
    *(uint4*)&As[buf][wofs] = ra0; *(uint4*)&As[buf][wofs + 8] = ra1;
    *(uint4*)&Bs[buf][wofs] = rb0; *(uint4*)&Bs[buf][wofs + 8] = rb1;
  };
  auto writeS = [&](int buf) {
    *(uint4*)&As[buf][wofs] = sa0; *(uint4*)&As[buf][wofs + 8] = sa1;
    *(uint4*)&Bs[buf][wofs] = sb0; *(uint4*)&Bs[buf][wofs + 8] = sb1;
  };
  auto computeBuf = [&](const unsigned short* as, const unsigned short* bs) {
    const int lk = kg * 8;
    short8v af[4], bfr[4];
#pragma unroll
    for (int mi = 0; mi < 4; ++mi)
      af[mi] = *(const short8v*)&as[(wr * 64 + mi * 16 + lm) * KPAD + lk];
#pragma unroll
    for (int nj = 0; nj < 4; ++nj)
      bfr[nj] = *(const short8v*)&bs[(wc * 64 + nj * 16 + lm) * KPAD + lk];
#pragma unroll
    for (int mi = 0; mi < 4; ++mi)
#pragma unroll
      for (int nj = 0; nj < 4; ++nj)
        acc[mi][nj] = __builtin_amdgcn_mfma_f32_16x16x32_bf16(af[mi], bfr[nj], acc[mi][nj], 0, 0, 0);
  };

  fetchR(kbeg);
  if (nt > 1) fetchS(kbeg + BK);
  writeR(0);
  if (nt > 2) fetchR(kbeg + 2 * BK);
  __syncthreads();

  for (int it = 0; it < nt; it += 2) {
    writeS(1);
    if (it + 3 < nt) fetchS(kbeg + (it + 3) * BK);
    computeBuf(&As[0][0], &Bs[0][0]);
    __syncthreads();
    if (it + 2 < nt) writeR(0);
    if (it + 4 < nt) fetchR(kbeg + (it + 4) * BK);
    computeBuf(&As[1][0], &Bs[1][0]);
    __syncthreads();
  }

  const int rbase = m0 + wr * 64;
  const int cbase = n0 + wc * 64;

  if constexpr (MODE == 0) {
#pragma unroll
    for (int mi = 0; mi < 4; ++mi)
#pragma unroll
      for (int r = 0; r < 4; ++r) {
        int grow = rbase + mi * 16 + kg * 4 + r;
#pragma unroll
        for (int nj = 0; nj < 4; ++nj) {
          int gcol = cbase + nj * 16 + lm;
          float t = acc[mi][nj][r] + (bias ? bias[gcol] : 0.f);
          float v = do_relu ? fmaxf(t, 0.f) : t;
          size_t idx = (size_t)grow * N + gcol;
          if constexpr (CBF16) __builtin_nontemporal_store(f2bf(v), (unsigned short*)Cv + idx);
          else                 __builtin_nontemporal_store(v, (float*)Cv + idx);
        }
      }
  } else if constexpr (MODE == 6) {
#pragma unroll
    for (int mi = 0; mi < 4; ++mi)
#pragma unroll
      for (int r = 0; r < 4; ++r) {
        int grow = rbase + mi * 16 + kg * 4 + r;
#pragma unroll
        for (int nj = 0; nj < 4; ++nj) {
          int gcol = cbase + nj * 16 + lm;
          int grp = gcol >> 10, col = gcol & 1023;
          float t = acc[mi][nj][r] + bias[gcol];
          float v = (grp == 3) ? fmaxf(x1[col] * t, 0.f) : t;
          __builtin_nontemporal_store(f2bf(v),
              (unsigned short*)Cv + ((size_t)grp * M + grow) * 1024 + col);
        }
      }
  } else if constexpr (MODE == 5) {
    size_t zofs = (size_t)bz * M;
#pragma unroll
    for (int mi = 0; mi < 4; ++mi)
#pragma unroll
      for (int r = 0; r < 4; ++r) {
        int grow = rbase + mi * 16 + kg * 4 + r;
#pragma unroll
        for (int nj = 0; nj < 4; ++nj) {
          int gcol = cbase + nj * 16 + lm;
          __builtin_nontemporal_store(acc[mi][nj][r], part + (zofs + grow) * N + gcol);
        }
      }
  } else if constexpr (MODE == 7) {
#pragma unroll
    for (int mi = 0; mi < 4; ++mi)
#pragma unroll
      for (int r = 0; r < 4; ++r) {
        int grow = rbase + mi * 16 + kg * 4 + r;
        int h = grow / NNN, n = grow - h * NNN;
        if (n == h) continue;
        long long orow = grow - h - (n > h ? 1 : 0);
#pragma unroll
        for (int nj = 0; nj < 4; ++nj) {
          int gcol = cbase + nj * 16 + lm;
          float v = fmaxf(acc[mi][nj][r] + biasUse[gcol], 0.f);
          __builtin_nontemporal_store(v, (float*)Cv + orow * 2048 + cofs + gcol);
        }
      }
  } else if constexpr (MODE == 1) {
#pragma unroll
    for (int mi = 0; mi < 4; ++mi)
#pragma unroll
      for (int r = 0; r < 4; ++r) {
        float s = 0.f;
#pragma unroll
        for (int nj = 0; nj < 4; ++nj) {
          int gcol = cbase + nj * 16 + lm;
          float v = fmaxf(acc[mi][nj][r] + bias[gcol], 0.f);
          s = fmaf(v, x1[gcol], s);
        }
#pragma unroll
        for (int off2 = 1; off2 < 16; off2 <<= 1) s += __shfl_xor(s, off2);
        if (lm == 0) red2[wr * 64 + mi * 16 + kg * 4 + r][wc] = s;
      }
    __syncthreads();
    if (tid < BM) {
      part[(size_t)(m0 + tid) * 8 + bx] = red2[tid][0] + red2[tid][1];
    }
  }
}

// V[p,j] = relu((uh[h,j] + un[n,j]) * vA[p*vstride+j])   (vA,V bf16)
__global__ __launch_bounds__(256) void tmulb_k(const unsigned short* __restrict__ vA,
    int vstride, const float* __restrict__ uh, const float* __restrict__ un,
    unsigned short* __restrict__ V)
{
  int p = blockIdx.x;
  int h = p / NNN, n = p - h * NNN;
  int j = threadIdx.x * 4;
  const float* uhr = uh + (size_t)h * NEC + j;
  const float* unr = un + (size_t)n * NEC + j;
  uint2 w = *(const uint2*)(vA + (size_t)p * vstride + j);
  float v0 = bf2f((unsigned short)(w.x & 0xffff));
  float v1 = bf2f((unsigned short)(w.x >> 16));
  float v2 = bf2f((unsigned short)(w.y & 0xffff));
  float v3 = bf2f((unsigned short)(w.y >> 16));
  float f0 = fmaxf((uhr[0] + unr[0]) * v0, 0.f);
  float f1 = fmaxf((uhr[1] + unr[1]) * v1, 0.f);
  float f2 = fmaxf((uhr[2] + unr[2]) * v2, 0.f);
  float f3 = fmaxf((uhr[3] + unr[3]) * v3, 0.f);
  unsigned lo = (unsigned)f2bf(f0) | ((unsigned)f2bf(f1) << 16);
  unsigned hi = (unsigned)f2bf(f2) | ((unsigned)f2bf(f3) << 16);
  nt_store8(lo, hi, V + (size_t)p * NEC + j);
}

// ---------------------------------------------------------------------------
// 256-thread unified GEMM (f32 A paths): MODE 0 only now (sp1, uG).
// ---------------------------------------------------------------------------
template<int MODE, int ABF16, int BBF16, int CBF16>
__global__ __launch_bounds__(256) void gemm_mfma(
    const void* __restrict__ Av, const void* __restrict__ Bv, long long ldbBlock,
    void* __restrict__ Cv, int M, int N, int K, int Ks,
    const float* __restrict__ bias, int do_relu,
    const float* __restrict__ x1, const float* __restrict__ x2,
    float* __restrict__ part, int colofs, int swz)
{
  __shared__ unsigned short As[BM * KPAD];
  __shared__ unsigned short Bs[BN * KPAD];

  const float* Af = (const float*)Av;
  const unsigned short* Ab = (const unsigned short*)Av;
  const float* Bf = (const float*)Bv;
  const unsigned short* Bb = (const unsigned short*)Bv;

  const int tid  = threadIdx.x;
  const int lane = tid & 63;
  const int wave = tid >> 6;
  const int wr = wave >> 1, wc = wave & 1;
  const int lm = lane & 15;
  const int kg = lane >> 4;

  int bx = blockIdx.x, by = blockIdx.y, bz = blockIdx.z;
  if (swz == 2) {
    int gy = gridDim.y;
    int ntile = gy * gridDim.z;
    int L = (bz * gy + by) * 8 + bx;
    int r = L & 7, q = L >> 3;
    int tpx = ntile >> 3;
    int tile = r * tpx + (q >> 3);
    bx = q & 7;
    bz = tile / gy;
    by = tile - bz * gy;
  }
  const int m0 = by * BM, n0 = bx * BN;
  const int kbeg = bz * Ks;
  const int kend = min(K, kbeg + Ks);

  f32x4 acc[4][4];
#pragma unroll
  for (int i = 0; i < 4; ++i)
#pragma unroll
    for (int j = 0; j < 4; ++j)
      acc[i][j] = (f32x4){0.f, 0.f, 0.f, 0.f};

  const int bn = tid & 127;
  const int kb = (tid >> 7) * 16;
  const float* bsrc = nullptr; long long bstride = 0;
  if constexpr (!BBF16) {
    int gcol = n0 + bn;
    if (ldbBlock) { bsrc = Bf + (long long)(gcol >> 6) * ldbBlock + (gcol & 63); bstride = 64; }
    else          { bsrc = Bf + gcol; bstride = N; }
  }

  uint4 pa0 = {0,0,0,0}, pa1 = {0,0,0,0};
  uint2 qa0 = {0,0}, qa1 = {0,0}, qa2 = {0,0}, qa3 = {0,0};
  uint4 pb0 = {0,0,0,0}, pb1 = {0,0,0,0};

  auto fetchA = [&](int k0) {
    if constexpr (ABF16) {
      int m = tid >> 1, kh = (tid & 1) * 16;
      int gm = m0 + m;
      pa0 = (uint4){0,0,0,0}; pa1 = (uint4){0,0,0,0};
      if (gm < M) {
        const uint4* s = (const uint4*)(Ab + (size_t)gm * K + k0 + kh);
        pa0 = s[0]; pa1 = s[1];
      }
    } else {
#define LOADA_F32(J, DST) { \
      int m = (tid >> 3) + J * 32; int k = (tid & 7) * 4; \
      int gm = m0 + m, gk = k0 + k; \
      float x0=0.f, x1v=0.f, x2v=0.f, x3=0.f; \
      if (gm < M) { const float* src = Af + (long long)gm * K + gk; \
        if (gk + 3 < K) { float4 v = *(const float4*)src; x0=v.x; x1v=v.y; x2v=v.z; x3=v.w; } \
        else { if (gk < K) x0 = src[0]; if (gk+1 < K) x1v = src[1]; \
               if (gk+2 < K) x2v = src[2]; if (gk+3 < K) x3 = src[3]; } } \
      DST.x = (unsigned)f2bf(x0)  | ((unsigned)f2bf(x1v) << 16); \
      DST.y = (unsigned)f2bf(x2v) | ((unsigned)f2bf(x3)  << 16); }
      LOADA_F32(0, qa0) LOADA_F32(1, qa1) LOADA_F32(2, qa2) LOADA_F32(3, qa3)
#undef LOADA_F32
    }
  };
  auto fetchB = [&](int k0) {
    if constexpr (BBF16) {
      int nrow = tid >> 1, kh = (tid & 1) * 16;
      const uint4* s = (const uint4*)(Bb + (size_t)(n0 + nrow) * K + k0 + kh);
      pb0 = s[0]; pb1 = s[1];
    } else {
#define PACKB(I, DST) { int g0 = k0 + kb + 2*I, g1 = g0 + 1; \
      float a = (g0 < K) ? bsrc[(long long)g0 * bstride] : 0.f; \
      float c = (g1 < K) ? bsrc[(long long)g1 * bstride] : 0.f; \
      DST = (unsigned)f2bf(a) | ((unsigned)f2bf(c) << 16); }
      PACKB(0, pb0.x) PACKB(1, pb0.y) PACKB(2, pb0.z) PACKB(3, pb0.w)
      PACKB(4, pb1.x) PACKB(5, pb1.y) PACKB(6, pb1.z) PACKB(7, pb1.w)
#undef PACKB
    }
  };
  auto stage = [&]() {
    if constexpr (ABF16) {
      int m = tid >> 1, kh = (tid & 1) * 16;
      *(uint4*)&As[m * KPAD + kh]     = pa0;
      *(uint4*)&As[m * KPAD + kh + 8] = pa1;
    } else {
      int m = tid >> 3, k = (tid & 7) * 4;
      *(uint2*)&As[(m      ) * KPAD + k] = qa0;
      *(uint2*)&As[(m +  32) * KPAD + k] = qa1;
      *(uint2*)&As[(m +  64) * KPAD + k] = qa2;
      *(uint2*)&As[(m +  96) * KPAD + k] = qa3;
    }
    if constexpr (BBF16) {
      int nrow = tid >> 1, kh = (tid & 1) * 16;
      *(uint4*)&Bs[nrow * KPAD + kh]     = pb0;
      *(uint4*)&Bs[nrow * KPAD + kh + 8] = pb1;
    } else {
      *(uint4*)&Bs[bn * KPAD + kb]     = pb0;
      *(uint4*)&Bs[bn * KPAD + kb + 8] = pb1;
    }
  };

  fetchA(kbeg); fetchB(kbeg);
  for (int k0 = kbeg; k0 < kend; k0 += BK) {
    stage();
    int kn = k0 + BK;
    if (kn < kend) { fetchA(kn); fetchB(kn); }
    __syncthreads();
    {
      const int lk = kg * 8;
      short8v af[4], bfr[4];
#pragma unroll
      for (int mi = 0; mi < 4; ++mi)
        af[mi] = *(const short8v*)&As[(wr * 64 + mi * 16 + lm) * KPAD + lk];
#pragma unroll
      for (int nj = 0; nj < 4; ++nj)
        bfr[nj] = *(const short8v*)&Bs[(wc * 64 + nj * 16 + lm) * KPAD + lk];
#pragma unroll
      for (int mi = 0; mi < 4; ++mi)
#pragma unroll
        for (int nj = 0; nj < 4; ++nj)
          acc[mi][nj] = __builtin_amdgcn_mfma_f32_16x16x32_bf16(af[mi], bfr[nj], acc[mi][nj], 0, 0, 0);
    }
    __syncthreads();
  }

  const int rbase = m0 + wr * 64;
  const int cbase = n0 + wc * 64;

  if constexpr (MODE == 0) {
#pragma unroll
    for (int mi = 0; mi < 4; ++mi)
#pragma unroll
      for (int r = 0; r < 4; ++r) {
        int grow = rbase + mi * 16 + kg * 4 + r;
        if (grow >= M) continue;
#pragma unroll
        for (int nj = 0; nj < 4; ++nj) {
          int gcol = cbase + nj * 16 + lm;
          float t = acc[mi][nj][r] + (bias ? bias[gcol] : 0.f);
          float v = do_relu ? fmaxf(t, 0.f) : t;
          size_t idx = (size_t)grow * N + gcol;
          if constexpr (CBF16) ((unsigned short*)Cv)[idx] = f2bf(v);
          else                 ((float*)Cv)[idx] = v;
        }
      }
  } else if constexpr (MODE == 5) {
    size_t zofs = (size_t)bz * M;
#pragma unroll
    for (int mi = 0; mi < 4; ++mi)
#pragma unroll
      for (int r = 0; r < 4; ++r) {
        int grow = rbase + mi * 16 + kg * 4 + r;
        if (grow >= M) continue;
#pragma unroll
        for (int nj = 0; nj < 4; ++nj) {
          int gcol = cbase + nj * 16 + lm;
          part[(zofs + grow) * N + gcol] = acc[mi][nj][r];
        }
      }
  }
}

// C[i] = maybe_relu(sum_z P[z*MN+i] + bias[i%N]); optional f32 and bf16 outs
__global__ __launch_bounds__(256) void ksum_k(const float* __restrict__ P,
    const float* __restrict__ bias, int do_relu, float* __restrict__ Cf,
    unsigned short* __restrict__ Cb, int MN, int N, int S)
{
  int i = blockIdx.x * 256 + threadIdx.x;
  if (i < MN) {
    float s = 0.f;
    for (int z = 0; z < S; ++z) s += __builtin_nontemporal_load(P + (size_t)z * MN + i);
    if (bias) s += bias[i % N];
    float v = do_relu ? fmaxf(s, 0.f) : s;
    if (Cf) Cf[i] = v;
    if (Cb) Cb[i] = f2bf(v);
  }
}

// group-routing ksum: P is [S][M][NG*1024]; column group g -> Cg[m*1024+col] + bg
__global__ __launch_bounds__(256) void ksumg_k(const float* __restrict__ P,
    const float* __restrict__ b0, const float* __restrict__ b1, const float* __restrict__ b2,
    float* __restrict__ C0, float* __restrict__ C1, float* __restrict__ C2,
    int M, int NG, int S)
{
  int i = blockIdx.x * 256 + threadIdx.x;
  int N = NG << 10;
  int total = M * N;
  if (i < total) {
    int m = i / N, c = i - m * N;
    int g = c >> 10, col = c & 1023;
    float s = 0.f;
    for (int z = 0; z < S; ++z) s += __builtin_nontemporal_load(P + (size_t)z * total + i);
    const float* b = g == 0 ? b0 : (g == 1 ? b1 : b2);
    if (b) s += b[col];
    float* C = g == 0 ? C0 : (g == 1 ? C1 : C2);
    C[(size_t)m * 1024 + col] = s;
  }
}

// tw[h,j] = sum_n soft[h,n] * relu(uO[n,j] * V[(h*384+n)*sV + j])  -> bf16
__global__ __launch_bounds__(256) void tw_k(const unsigned short* __restrict__ V, int sV,
    const float* __restrict__ uO, const float* __restrict__ soft,
    unsigned short* __restrict__ tw)
{
  int h = blockIdx.x;
  int j = blockIdx.y * 256 + threadIdx.x;
  const float* srow = soft + h * NNN;
  float s = 0.f;
  for (int n = 0; n < NNN; ++n) {
    float v = bf2f(V[((size_t)h * NNN + n) * sV + j]);
    float t = fmaxf(uO[(size_t)n * NEC + j] * v, 0.f);
    s = fmaf(srow[n], t, s);
  }
  tw[(size_t)h * NEC + j] = f2bf(s);
}

// two[n,j] = sum_h softT[n,h] * relu(uS[h,j] * V[(h*384+n)*sV + j])  -> bf16
__global__ __launch_bounds__(256) void two_k(const unsigned short* __restrict__ V, int sV,
    const float* __restrict__ uS, const float* __restrict__ softT,
    unsigned short* __restrict__ two)
{
  int n = blockIdx.x;
  int j = blockIdx.y * 256 + threadIdx.x;
  const float* srow = softT + n * NHH;
  float s = 0.f;
#pragma unroll 8
  for (int h = 0; h < NHH; ++h) {
    float v = bf2f(V[((size_t)h * NNN + n) * sV + j]);
    float t = fmaxf(uS[(size_t)h * NEC + j] * v, 0.f);
    s = fmaf(srow[h], t, s);
  }
  two[(size_t)n * NEC + j] = f2bf(s);
}

// fused adj-finalize + both softmaxes. grid (NHH+NNN, 64 thr)
__global__ __launch_bounds__(64) void softmax2_k(const float* __restrict__ part,
    const float* __restrict__ badj, float* __restrict__ soft, float* __restrict__ softT)
{
  int b = blockIdx.x, t = threadIdx.x;
  float b0 = badj[0];
  if (b < NHH) {
    __shared__ float buf[NNN];
    int h = b;
    float mx = -1e30f;
    for (int n = t; n < NNN; n += 64) {
      size_t p = (size_t)(h * NNN + n) * 8;
      float s = b0;
#pragma unroll
      for (int c = 0; c < 8; ++c) s += part[p + c];
      buf[n] = s;
      mx = fmaxf(mx, s);
    }
#pragma unroll
    for (int off = 32; off >= 1; off >>= 1) mx = fmaxf(mx, __shfl_xor(mx, off));
    float s = 0.f;
    for (int n = t; n < NNN; n += 64) { float e = expf(buf[n] - mx); buf[n] = e; s += e; }
#pragma unroll
    for (int off = 32; off >= 1; off >>= 1) s += __shfl_xor(s, off);
    float inv = 1.f / s;
    for (int n = t; n < NNN; n += 64) soft[h * NNN + n] = buf[n] * inv;
  } else {
    int n = b - NHH;
    float v = -1e30f;
    if (t < NHH) {
      size_t p = (size_t)(t * NNN + n) * 8;
      v = b0;
#pragma unroll
      for (int c = 0; c < 8; ++c) v += part[p + c];
    }
    float mx = v;
#pragma unroll
    for (int off = 32; off >= 1; off >>= 1) mx = fmaxf(mx, __shfl_xor(mx, off));
    float e = (t < NHH) ? expf(v - mx) : 0.f;
    float s = e;
#pragma unroll
    for (int off = 32; off >= 1; off >>= 1) s += __shfl_xor(s, off);
    if (t < NHH) softT[n * NHH + t] = e / s;
  }
}

// out = LN(x+m)*g+b; optional bf16 mirror
__global__ __launch_bounds__(256) void ln_k(const float* __restrict__ x, const float* __restrict__ m,
    const float* __restrict__ g, const float* __restrict__ b, float* __restrict__ out,
    unsigned short* __restrict__ outb)
{
  int r = blockIdx.x, t = threadIdx.x;
  __shared__ float rs[4], rs2[4];
  const float* xr = x + (size_t)r * NEC;
  const float* mr = m + (size_t)r * NEC;
  float s = 0.f, s2 = 0.f;
  for (int j = t; j < NEC; j += 256) { float v = xr[j] + mr[j]; s += v; s2 = fmaf(v, v, s2); }
#pragma unroll
  for (int off = 32; off >= 1; off >>= 1) { s += __shfl_xor(s, off); s2 += __shfl_xor(s2, off); }
  if ((t & 63) == 0) { rs[t >> 6] = s; rs2[t >> 6] = s2; }
  __syncthreads();
  s = rs[0] + rs[1] + rs[2] + rs[3];
  s2 = rs2[0] + rs2[1] + rs2[2] + rs2[3];
  float mean = s * (1.f / NEC);
  float var = s2 * (1.f / NEC) - mean * mean;
  float rstd = rsqrtf(var + 1e-5f);
  float* o = out + (size_t)r * NEC;
  unsigned short* ob = outb ? outb + (size_t)r * NEC : nullptr;
  for (int j = t; j < NEC; j += 256) {
    float v = xr[j] + mr[j];
    float w = (v - mean) * rstd * g[j] + b[j];
    o[j] = w;
    if (ob) ob[j] = f2bf(w);
  }
}

__global__ __launch_bounds__(64) void gfeat_k(const float* __restrict__ feat3,
                                              float* __restrict__ gfeat)
{
  int ch = blockIdx.x, t = threadIdx.x;
  float s = 0.f;
  for (int i = t; i < 625; i += 64) s += feat3[ch * 625 + i];
#pragma unroll
  for (int off = 32; off >= 1; off >>= 1) s += __shfl_xor(s, off);
  if (t == 0) gfeat[ch] = s * (1.f / 625.f);
}

extern "C" void kernel_launch(void* const* d_in, const int* in_sizes, int n_in,
                              void* d_out, int out_size, void* d_ws, size_t ws_size,
                              hipStream_t stream)
{
  const float* box   = (const float*)d_in[0];
  const float* feat3 = (const float*)d_in[1];
  const float* sp36  = (const float*)d_in[2];
  const float* Wbh1  = (const float*)d_in[3];
  const float* bbh1  = (const float*)d_in[4];
  const float* Wbh2  = (const float*)d_in[5];
  const float* bbh2  = (const float*)d_in[6];
  const float* Wsp1  = (const float*)d_in[7];
  const float* bsp1  = (const float*)d_in[8];
  const float* Wsp2  = (const float*)d_in[9];
  const float* bsp2  = (const float*)d_in[10];
  const float* Wsp3  = (const float*)d_in[11];
  const float* bsp3  = (const float*)d_in[12];
  const float* Wadj  = (const float*)d_in[13];
  const float* badj  = (const float*)d_in[14];
  const float* A1W = (const float*)d_in[15]; const float* A1b = (const float*)d_in[16];
  const float* A2W = (const float*)d_in[17]; const float* A2b = (const float*)d_in[18];
  const float* A3W = (const float*)d_in[19]; const float* A3b = (const float*)d_in[20];
  const float* O1W = (const float*)d_in[21]; const float* O1b = (const float*)d_in[22];
  const float* O2W = (const float*)d_in[23]; const float* O2b = (const float*)d_in[24];
  const float* O3W = (const float*)d_in[25]; const float* O3b = (const float*)d_in[26];
  const float* S1W = (const float*)d_in[27]; const float* S1b = (const float*)d_in[28];
  const float* S2W = (const float*)d_in[29]; const float* S2b = (const float*)d_in[30];
  const float* S3W = (const float*)d_in[31]; const float* S3b = (const float*)d_in[32];
  const float* G1W = (const float*)d_in[33]; const float* G1b = (const float*)d_in[34];
  const float* G2W = (const float*)d_in[35]; const float* G2b = (const float*)d_in[36];
  const float* G3W = (const float*)d_in[37]; const float* G3b = (const float*)d_in[38];
  const float* gln_h = (const float*)d_in[39]; const float* bln_h = (const float*)d_in[40];
  const float* gln_o = (const float*)d_in[41]; const float* bln_o = (const float*)d_in[42];
  (void)in_sizes; (void)n_in; (void)out_size; (void)ws_size;

  // ---- workspace carve ----
  char* base = (char*)d_ws;
  unsigned short* VQ  = (unsigned short*)base;            // 4 x [NP][1024] bf16 (151 MB total)
  unsigned short* VAq = VQ + (size_t)0 * NP * 1024;       // vA
  unsigned short* VOq = VQ + (size_t)1 * NP * 1024;       // vO
  unsigned short* VSq = VQ + (size_t)2 * NP * 1024;       // vS
  unsigned short* VGq = VQ + (size_t)3 * NP * 1024;       // t_glob
  float* partialV4    = (float*)base;                     // early split-K partials (box, node MLP)
  unsigned short* Vb  = (unsigned short*)(base + (size_t)NP * 4096 * 2);  // [NP][1024] bf16
  float* partialVb    = (float*)Vb;
  unsigned short* s1  = Vb;                               // sp stage 1 alias
  unsigned short* s2  = Vb + (size_t)NP * 128;            // sp stage 2 alias
  unsigned short* SPb = Vb + (size_t)NP * 1024;           // [NP][1024] bf16
  float* f = (float*)(SPb + (size_t)NP * 1024);
  size_t off = 0;
  auto alloc = [&](size_t n) { float* p = f + off; off += n; return p; };
  float* node1 = alloc(384 * NEC);
  float* node  = alloc(384 * NEC);
  float* hnode1= alloc(128 * NEC);
  float* node2 = alloc(384 * NEC);
  float* uhA   = alloc(384 * NEC);
  float* unA   = alloc(384 * NEC);
  float* uO    = alloc(384 * NEC);
  float* uS    = alloc(128 * NEC);
  float* uh2   = alloc(128 * NEC);
  float* un2   = alloc(384 * NEC);
  float* uG    = alloc(NEC);
  float* gfeat = alloc(256);
  float* b3A = alloc(NEC); float* b3O = alloc(NEC); float* b3S = alloc(NEC); float* b3G = alloc(NEC);
  float* bias4 = alloc(4096);
  float* part  = alloc((size_t)NP * 8);
  float* adj   = alloc(NP);
  float* soft  = alloc(NP);
  float* softT = alloc(NP);
  float* m_h   = alloc(128 * NEC);      // padded to 128 rows (ksum writes full pad)
  float* m_o   = alloc(384 * NEC);
  // bf16 converted operands (persist whole call)
  unsigned short* wb = (unsigned short*)(f + off);
  size_t wo = 0;
  auto walloc = [&](size_t n) { unsigned short* p = wb + wo; wo += n; return p; };
  unsigned short* W4b   = walloc((size_t)4 * MB1);        // [A2|O2|S2|G2]^T [4096][1024]
  unsigned short* A3Wb  = walloc((size_t)MB1);
  unsigned short* G3Wb  = walloc((size_t)MB1);
  unsigned short* O3Wb  = walloc((size_t)MB1);
  unsigned short* S3Wb  = walloc((size_t)MB1);
  unsigned short* Wsp3b = walloc((size_t)NEC * 256);
  unsigned short* Wsp2b = walloc((size_t)256 * 128);
  unsigned short* Wbh1b = walloc((size_t)NEC * 12544);
  unsigned short* Wbh2b = walloc((size_t)MB1);
  unsigned short* U1b   = walloc((size_t)3 * MB1);        // [W1h|W1n|O1W]^T [3072][1024]
  unsigned short* U2b   = walloc((size_t)2 * MB1);        // [S1W|W1h]^T [2048][1024]
  unsigned short* boxb  = walloc((size_t)384 * 12544);
  unsigned short* nodeb = walloc((size_t)384 * NEC);
  unsigned short* node1b= walloc((size_t)384 * NEC);
  unsigned short* hnode1b = walloc((size_t)128 * NEC);
  unsigned short* node2b  = walloc((size_t)384 * NEC);
  unsigned short* twbb  = walloc((size_t)128 * NEC);      // tw bf16, padded rows
  unsigned short* twobb = walloc((size_t)384 * NEC);      // two bf16

  auto convw = [&](const float* W, unsigned short* out, int inK, int outK, int N,
                   int blocked, int koff) {
    dim3 g(outK / 64, N / 64);
    hipLaunchKernelGGL(convw_k, g, dim3(256), 0, stream, W, out, inK, outK, N, blocked, koff);
  };

  // ---- one-time conversions: 14 x [1024][1024] jobs in ONE launch ----
  {
    CJobs J;
    J.src[0]=A2W;  J.dst[0]=W4b+0*MB1;   J.inK[0]=1024; J.koff[0]=0;    J.blocked[0]=1;
    J.src[1]=O2W;  J.dst[1]=W4b+1*MB1;   J.inK[1]=1024; J.koff[1]=0;    J.blocked[1]=1;
    J.src[2]=S2W;  J.dst[2]=W4b+2*MB1;   J.inK[2]=1024; J.koff[2]=0;    J.blocked[2]=1;
    J.src[3]=G2W;  J.dst[3]=W4b+3*MB1;   J.inK[3]=1024; J.koff[3]=0;    J.blocked[3]=1;
    J.src[4]=A1W;  J.dst[4]=U1b+0*MB1;   J.inK[4]=2048; J.koff[4]=0;    J.blocked[4]=1;
    J.src[5]=A1W;  J.dst[5]=U1b+1*MB1;   J.inK[5]=2048; J.koff[5]=1024; J.blocked[5]=1;
    J.src[6]=O1W;  J.dst[6]=U1b+2*MB1;   J.inK[6]=1024; J.koff[6]=0;    J.blocked[6]=1;
    J.src[7]=S1W;  J.dst[7]=U2b+0*MB1;   J.inK[7]=1024; J.koff[7]=0;    J.blocked[7]=1;
    J.src[8]=A1W;  J.dst[8]=U2b+1*MB1;   J.inK[8]=2048; J.koff[8]=0;    J.blocked[8]=1;
    J.src[9]=A3W;  J.dst[9]=A3Wb;        J.inK[9]=1024; J.koff[9]=0;    J.blocked[9]=0;
    J.src[10]=G3W; J.dst[10]=G3Wb;       J.inK[10]=1024;J.koff[10]=0;   J.blocked[10]=0;
    J.src[11]=Wbh2;J.dst[11]=Wbh2b;      J.inK[11]=1024;J.koff[11]=0;   J.blocked[11]=0;
    J.src[12]=O3W; J.dst[12]=O3Wb;       J.inK[12]=1024;J.koff[12]=0;   J.blocked[12]=0;
    J.src[13]=S3W; J.dst[13]=S3Wb;       J.inK[13]=1024;J.koff[13]=0;   J.blocked[13]=0;
    hipLaunchKernelGGL(convjobs_k, dim3(16, 16, 14), dim3(256), 0, stream, J);
  }
  convw(Wsp3, Wsp3b, 256, 256, NEC, 0, 0);
  convw(Wsp2, Wsp2b, 128, 128, 256, 0, 0);
  convw(Wbh1, Wbh1b, 12544, 12544, NEC, 0, 0);
  cvt_k<<<(384 * 12544 / 4 + 255) / 256, 256, 0, stream>>>(box, boxb, 384 * 12544);

  gfeat_k<<<256, 64, 0, stream>>>(feat3, gfeat);
  {
    Ptr4 P; P.s[0]=A3b; P.s[1]=O3b; P.s[2]=S3b; P.s[3]=G3b;
    P.d[0]=b3A; P.d[1]=b3O; P.d[2]=b3S; P.d[3]=b3G;
    hipLaunchKernelGGL(b3sum4_k, dim3(4, 4), dim3(256), 0, stream, P);
  }
  biascat4_k<<<16, 256, 0, stream>>>(A2b, O2b, S2b, G2b, bias4);

  // ---- node MLP (partials in dead VQ region; bf16 outs fused into ksum) ----
  {
    dim3 grid(8, 3, 16);                         // box: S=16, Ks=832
    hipLaunchKernelGGL((gemm_db<5, 0>), grid, dim3(256), 0, stream,
                       boxb, 12544, Wbh1b, 12544, nullptr, 384, NEC, 12544, 832,
                       nullptr, 0, nullptr, nullptr, partialV4, 0, 2);
    hipLaunchKernelGGL(ksum_k, dim3((384 * NEC + 255) / 256), dim3(256), 0, stream,
                       partialV4, bbh1, 1, (float*)nullptr, node1b, 384 * NEC, NEC, 16);
  }
  {
    dim3 grid(8, 3, 8);                          // Ks=128, 4 tiles/slice
    hipLaunchKernelGGL((gemm_db<5, 0>), grid, dim3(256), 0, stream,
                       node1b, NEC, Wbh2b, NEC, nullptr, 384, NEC, NEC, 128,
                       nullptr, 0, nullptr, nullptr, partialV4, 0, 2);
    hipLaunchKernelGGL(ksum_k, dim3((384 * NEC + 255) / 256), dim3(256), 0, stream,
                       partialV4, bbh2, 1, node, nodeb, 384 * NEC, NEC, 8);
  }

  // ---- spatial MLP -> SPb (s1/s2 alias Vb) ----
  {
    dim3 g1(1, NP / BM);
    hipLaunchKernelGGL((gemm_mfma<0, 0, 0, 1>), g1, dim3(256), 0, stream,
                       sp36, Wsp1, 0LL, s1, NP, 128, 36, 36, bsp1, 1, nullptr, nullptr, nullptr, 0, 0);
    dim3 g2(2, NP / BM);
    hipLaunchKernelGGL((gemm_db<0, 1>), g2, dim3(256), 0, stream,
                       s1, 128, Wsp2b, 128, s2, NP, 256, 128, 128, bsp2, 1,
                       nullptr, nullptr, nullptr, 0, 0);
    dim3 g3(8, NP / BM);
    hipLaunchKernelGGL((gemm_db<0, 1>), g3, dim3(256), 0, stream,
                       s2, 256, Wsp3b, 256, SPb, NP, NEC, 256, 256, bsp3, 1,
                       nullptr, nullptr, nullptr, 0, 1);
  }

  // ---- uG (tiny, must precede FUSED4) ----
  {
    dim3 g1(8, 1);
    hipLaunchKernelGGL((gemm_mfma<0, 0, 0, 0>), g1, dim3(256), 0, stream,
                       gfeat, G1W, 256LL * 64, uG, 1, NEC, 256, 256, G1b, 0,
                       nullptr, nullptr, nullptr, 0, 0);
  }

  // ---- FUSED4: {vA,vO,vS,tG} = SPb @ [A2|O2|S2|G2] -> 4 contiguous buffers ----
  {
    dim3 grid(32, NP / BM);
    hipLaunchKernelGGL((gemm_db<6, 1>), grid, dim3(256), 0, stream,
                       SPb, NEC, W4b, NEC, VQ, NP, 4096, NEC, NEC,
                       bias4, 0, uG, nullptr, nullptr, 0, 3);
  }

  // ---- U1: [uhA|unA|uO] = node @ [W1h|W1n|O1W] ----
  {
    dim3 grid(24, 3, 8);                         // Ks=128
    hipLaunchKernelGGL((gemm_db<5, 0>), grid, dim3(256), 0, stream,
                       nodeb, NEC, U1b, NEC, nullptr, 384, 3072, NEC, 128,
                       nullptr, 0, nullptr, nullptr, partialVb, 0, 0);
    int total = 384 * 3072;
    hipLaunchKernelGGL(ksumg_k, dim3((total + 255) / 256), dim3(256), 0, stream,
                       partialVb, A1b, (const float*)nullptr, O1b, uhA, unA, uO, 384, 3, 8);
  }

  // ---- adjacency head ----
  tmulb_k<<<NP, 256, 0, stream>>>(VAq, 1024, uhA, unA, Vb);      // V = relu((uh+un)*vA)
  {
    dim3 g(8, NP / BM);
    hipLaunchKernelGGL((gemm_db<1, 0>), g, dim3(256), 0, stream,
                       Vb, NEC, A3Wb, NEC, nullptr, NP, NEC, NEC, NEC,
                       b3A, 1, Wadj, nullptr, part, 0, 1);
  }
  softmax2_k<<<NHH + NNN, 64, 0, stream>>>(part, badj, soft, softT);

  // ---- m_h (O head): vO contiguous; tw -> bf16 -> bf16 GEMM ----
  tw_k<<<dim3(NHH, 4), 256, 0, stream>>>(VOq, 1024, uO, soft, twbb);
  {
    dim3 grid(8, 1, 8);                          // M padded to 128; Ks=128; swz=2 (gy*gz=8)
    hipLaunchKernelGGL((gemm_db<5, 0>), grid, dim3(256), 0, stream,
                       twbb, NEC, O3Wb, NEC, nullptr, 128, NEC, NEC, 128,
                       nullptr, 0, nullptr, nullptr, partialVb, 0, 2);
    hipLaunchKernelGGL(ksum_k, dim3((128 * NEC + 255) / 256), dim3(256), 0, stream,
                       partialVb, b3O, 1, m_h, (unsigned short*)nullptr, 128 * NEC, NEC, 8);
  }
  ln_k<<<NHH, 256, 0, stream>>>(node, m_h, gln_h, bln_h, hnode1, hnode1b);

  // ---- U2: [uS|uh2] = hnode1 @ [S1W|W1h] ----
  {
    dim3 grid(16, 1, 8);
    hipLaunchKernelGGL((gemm_db<5, 0>), grid, dim3(256), 0, stream,
                       hnode1b, NEC, U2b, NEC, nullptr, 128, 2048, NEC, 128,
                       nullptr, 0, nullptr, nullptr, partialVb, 0, 0);
    int total = 128 * 2048;
    hipLaunchKernelGGL(ksumg_k, dim3((total + 255) / 256), dim3(256), 0, stream,
                       partialVb, S1b, A1b, (const float*)nullptr, uS, uh2, (float*)nullptr, 128, 2, 8);
  }

  // ---- m_o (S head): vS contiguous; two -> bf16 -> bf16 GEMM ----
  two_k<<<dim3(NNN, 4), 256, 0, stream>>>(VSq, 1024, uS, softT, twobb);
  {
    dim3 grid(8, 3, 8);                          // Ks=128; swz=2 (gy*gz=24)
    hipLaunchKernelGGL((gemm_db<5, 0>), grid, dim3(256), 0, stream,
                       twobb, NEC, S3Wb, NEC, nullptr, 384, NEC, NEC, 128,
                       nullptr, 0, nullptr, nullptr, partialVb, 0, 2);
    hipLaunchKernelGGL(ksum_k, dim3((384 * NEC + 255) / 256), dim3(256), 0, stream,
                       partialVb, b3S, 1, m_o, (unsigned short*)nullptr, 384 * NEC, NEC, 8);
  }
  ln_k<<<NNN, 256, 0, stream>>>(node, m_o, gln_o, bln_o, node2, node2b);

  // ---- un2 = node2 @ W1n ----
  {
    dim3 grid(8, 3, 8);
    hipLaunchKernelGGL((gemm_db<5, 0>), grid, dim3(256), 0, stream,
                       node2b, NEC, U1b + 1 * MB1, NEC, nullptr, 384, NEC, NEC, 128,
                       nullptr, 0, nullptr, nullptr, partialVb, 0, 2);
    hipLaunchKernelGGL(ksum_k, dim3((384 * NEC + 255) / 256), dim3(256), 0, stream,
                       partialVb, (const float*)nullptr, 0, un2, (unsigned short*)nullptr, 384 * NEC, NEC, 8);
  }

  // ---- f_pair V (reuses contiguous vA) ----
  tmulb_k<<<NP, 256, 0, stream>>>(VAq, 1024, uh2, un2, Vb);

  // ---- merged output GEMM: f_pair (bx<8) + f_glob (bx>=8, contiguous tG) ----
  {
    dim3 g(16, NP / BM);
    hipLaunchKernelGGL((gemm_db<7, 0>), g, dim3(256), 0, stream,
                       Vb, NEC, A3Wb, NEC, (float*)d_out, NP, NEC, NEC, NEC,
                       b3A, 1, (const float*)VGq, (const float*)G3Wb,
                       b3G, 0, 3);
  }
}

// Round 23
// 751.199 us; speedup vs baseline: 1.0491x; 1.0491x over previous
//
#include <hip/hip_runtime.h>
#include <math.h>

#define NHH 48
#define NNN 384
#define NP  18432   // NHH*NNN
#define NEC 1024
#define MB1 (1024*1024)

#define BM 128
#define BN 128
#define BK 32
#define KPAD 40     // padded bf16 elems per LDS row

typedef __attribute__((ext_vector_type(8))) short short8v;   // 8 bf16 (4 VGPR)
typedef __attribute__((ext_vector_type(4))) float f32x4;     // MFMA acc

__device__ __forceinline__ unsigned short f2bf(float x) {
  unsigned int u = __float_as_uint(x);
  u += 0x7fffu + ((u >> 16) & 1u);   // RNE
  return (unsigned short)(u >> 16);
}
__device__ __forceinline__ float bf2f(unsigned short b) {
  return __uint_as_float(((unsigned)b) << 16);
}

// ---------------------------------------------------------------------------
// Weight pre-convert: f32 -> bf16 transposed [N][outK], k in [koff, koff+outK).
// ---------------------------------------------------------------------------
__global__ __launch_bounds__(256) void convw_k(const float* __restrict__ in,
    unsigned short* __restrict__ out, int inK, int outK, int N, int blocked, int koff)
{
  __shared__ float t[64][65];
  int kb = blockIdx.x * 64, nb = blockIdx.y * 64;
  const float* src; size_t stride;
  if (blocked) { src = in + (size_t)(nb >> 6) * inK * 64; stride = 64; }
  else         { src = in + nb; stride = N; }
  for (int i = threadIdx.x; i < 64 * 64; i += 256) {
    int k = i >> 6, d = i & 63;
    t[d][k] = src[(size_t)(kb + koff + k) * stride + d];
  }
  __syncthreads();
  for (int i = threadIdx.x; i < 64 * 64; i += 256) {
    int d = i >> 6, k = i & 63;
    out[(size_t)(nb + d) * outK + kb + k] = f2bf(t[d][k]);
  }
}

// 14 same-shape [1024][1024] conversions in one launch (z = job)
struct CJobs {
  const float* src[14];
  unsigned short* dst[14];
  int inK[14];
  int koff[14];
  int blocked[14];
};
__global__ __launch_bounds__(256) void convjobs_k(CJobs J)
{
  __shared__ float t[64][65];
  int z = blockIdx.z;
  const float* in = J.src[z];
  unsigned short* out = J.dst[z];
  int inK = J.inK[z], koff = J.koff[z], blocked = J.blocked[z];
  int kb = blockIdx.x * 64, nb = blockIdx.y * 64;
  const float* src; size_t stride;
  if (blocked) { src = in + (size_t)(nb >> 6) * inK * 64; stride = 64; }
  else         { src = in + nb; stride = NEC; }
  for (int i = threadIdx.x; i < 64 * 64; i += 256) {
    int k = i >> 6, d = i & 63;
    t[d][k] = src[(size_t)(kb + koff + k) * stride + d];
  }
  __syncthreads();
  for (int i = threadIdx.x; i < 64 * 64; i += 256) {
    int d = i >> 6, k = i & 63;
    out[(size_t)(nb + d) * NEC + kb + k] = f2bf(t[d][k]);
  }
}

// elementwise f32 -> bf16 (n multiple of 4)
__global__ __launch_bounds__(256) void cvt_k(const float* __restrict__ in,
    unsigned short* __restrict__ out, int n)
{
  int i = (blockIdx.x * 256 + threadIdx.x) * 4;
  if (i < n) {
    float4 v = *(const float4*)(in + i);
    uint2 o;
    o.x = (unsigned)f2bf(v.x) | ((unsigned)f2bf(v.y) << 16);
    o.y = (unsigned)f2bf(v.z) | ((unsigned)f2bf(v.w) << 16);
    *(uint2*)(out + i) = o;
  }
}

// b3 sums for all four heads in one launch (y = head)
struct Ptr4 { const float* s[4]; float* d[4]; };
__global__ __launch_bounds__(256) void b3sum4_k(Ptr4 P)
{
  int r = blockIdx.x * 256 + threadIdx.x;
  const float* b3 = P.s[blockIdx.y];
  float* out = P.d[blockIdx.y];
  if (r < NEC) {
    float s = 0.f;
#pragma unroll
    for (int c = 0; c < 16; ++c) s += b3[c * NEC + r];
    out[r] = s;
  }
}

// bias4[j] = b_{j>>10}[j&1023]
__global__ __launch_bounds__(256) void biascat4_k(const float* __restrict__ b0,
    const float* __restrict__ b1, const float* __restrict__ b2,
    const float* __restrict__ b3, float* __restrict__ out)
{
  int j = blockIdx.x * 256 + threadIdx.x;
  if (j < 4096) {
    int g = j >> 10, c = j & 1023;
    const float* b = g == 0 ? b0 : (g == 1 ? b1 : (g == 2 ? b2 : b3));
    out[j] = b[c];
  }
}

// ---------------------------------------------------------------------------
// gemm_db: 256 thr / 4 waves / 64x64-per-wave bf16 GEMM, double-buffered LDS
// (ONE barrier per K-step), 2-deep register prefetch. A [M][lda], B [N][ldb].
// Split-K via blockIdx.z (Ks multiple of 64, exact cover).
// swz=1: bx-inner bijective XCD remap; grid (gx,144,1).
// swz=2: 3D split-K XCD remap; grid (8, gy, gz), gy*gz % 8 == 0.
// swz=3: phase-grouped remap, grid (gx,144), gx in {16,32}: gx/8 phases.
// MODE 0: C = maybe_relu(acc + bias)
// MODE 1: part[grow*8+bx] = sum_j relu(acc+bias)*x1[j]
// MODE 5: part[(z*M+grow)*N + j] = acc
// MODE 6: fused4 epilogue (N=4096): t=acc+bias[gcol]; group (gcol>>10) routed
//         to FOUR contiguous [M][1024] bf16 buffers at Cv + grp*M*1024;
//         group3 -> relu(x1[col]*t).
// MODE 7: merged output (grid (16,144), swz=3): bx<8 -> {A,B,bias,colofs=0};
//         bx>=8 -> {A=(ushort*)x1 lda 1024 (contig Vg3), B=(ushort*)x2
//         ldb 1024, bias=part, colofs=1024}. Row-remapped store, skip diag.
// ---------------------------------------------------------------------------
template<int MODE, int CBF16>
__global__ __launch_bounds__(256) void gemm_db(
    const unsigned short* __restrict__ A, int lda,
    const unsigned short* __restrict__ B, int ldb,
    void* __restrict__ Cv, int M, int N, int K, int Ks,
    const float* __restrict__ bias, int do_relu,
    const float* __restrict__ x1, const float* __restrict__ x2,
    float* __restrict__ part, int colofs, int swz)
{
  __shared__ unsigned short As[2][BM * KPAD];
  __shared__ unsigned short Bs[2][BN * KPAD];
  __shared__ float red2[BM][2];

  const int tid  = threadIdx.x;
  const int lane = tid & 63;
  const int wave = tid >> 6;
  const int wr = wave >> 1, wc = wave & 1;
  const int lm = lane & 15;
  const int kg = lane >> 4;

  int bx = blockIdx.x, by = blockIdx.y;
  int bz = blockIdx.z;
  if (swz == 1) {                   // grid (gx,144): bx-inner bijective remap
    int gx = gridDim.x;
    int L = by * gx + bx;
    int r = L & 7, q = L >> 3;      // r = XCD class
    bx = q % gx;
    by = r + 8 * (q / gx);
  } else if (swz == 2) {            // grid (8, gy, gz), gy*gz % 8 == 0
    int gy = gridDim.y;
    int ntile = gy * gridDim.z;
    int L = (bz * gy + by) * 8 + bx;
    int r = L & 7, q = L >> 3;
    int tpx = ntile >> 3;
    int tile = r * tpx + (q >> 3);
    bx = q & 7;
    bz = tile / gy;
    by = tile - bz * gy;
  } else if (swz == 3) {            // grid (gx,144): (gx/8) phases x 8 bx
    int gx = gridDim.x;
    int L = by * gx + bx;
    int p = L / 1152, rem = L - p * 1152;
    int r = rem & 7, q = rem >> 3;  // q in 0..143
    bx = p * 8 + (q & 7);
    by = r + 8 * (q >> 3);
  }

  // per-block operand selection (MODE 7 routes by bx group)
  const unsigned short* Ause = A; int ldause = lda;
  const unsigned short* Buse = B; int ldbuse = ldb;
  const float* biasUse = bias;    int cofs = colofs;
  int bxl = bx;
  if constexpr (MODE == 7) {
    if (bx >= 8) {
      Ause = (const unsigned short*)x1; ldause = 1024;   // contiguous Vg3
      Buse = (const unsigned short*)x2; ldbuse = 1024;
      biasUse = part; cofs = 1024;
    }
    bxl = bx & 7;
  }
  const int m0 = by * BM, n0 = bxl * BN;
  const int kbeg = bz * Ks;
  const int kend = min(K, kbeg + Ks);
  const int nt = (kend - kbeg) / BK;   // even by construction

  f32x4 acc[4][4];
#pragma unroll
  for (int i = 0; i < 4; ++i)
#pragma unroll
    for (int j = 0; j < 4; ++j)
      acc[i][j] = (f32x4){0.f, 0.f, 0.f, 0.f};

  const int sr = tid >> 1;
  const int sc = (tid & 1) * 16;
  const unsigned short* aP = Ause + (size_t)(m0 + sr) * ldause + sc;
  const unsigned short* bP = Buse + (size_t)(n0 + sr) * ldbuse + sc;
  const int wofs = sr * KPAD + sc;

  uint4 ra0, ra1, rb0, rb1;   // slot R (even tiles)
  uint4 sa0, sa1, sb0, sb1;   // slot S (odd tiles)

  auto fetchR = [&](int k0) {
    ra0 = *(const uint4*)(aP + k0); ra1 = *(const uint4*)(aP + k0 + 8);
    rb0 = *(const uint4*)(bP + k0); rb1 = *(const uint4*)(bP + k0 + 8);
  };
  auto fetchS = [&](int k0) {
    sa0 = *(const uint4*)(aP + k0); sa1 = *(const uint4*)(aP + k0 + 8);
    sb0 = *(const uint4*)(bP + k0); sb1 = *(const uint4*)(bP + k0 + 8);
  };
  auto writeR = [&](int buf) {
    *(uint4*)&As[buf][wofs] = ra0; *(uint4*)&As[buf][wofs + 8] = ra1;
    *(uint4*)&Bs[buf][wofs] = rb0; *(uint4*)&Bs[buf][wofs + 8] = rb1;
  };
  auto writeS = [&](int buf) {
    *(uint4*)&As[buf][wofs] = sa0; *(uint4*)&As[buf][wofs + 8] = sa1;
    *(uint4*)&Bs[buf][wofs] = sb0; *(uint4*)&Bs[buf][wofs + 8] = sb1;
  };
  auto computeBuf = [&](const unsigned short* as, const unsigned short* bs) {
    const int lk = kg * 8;
    short8v af[4], bfr[4];
#pragma unroll
    for (int mi = 0; mi < 4; ++mi)
      af[mi] = *(const short8v*)&as[(wr * 64 + mi * 16 + lm) * KPAD + lk];
#pragma unroll
    for (int nj = 0; nj < 4; ++nj)
      bfr[nj] = *(const short8v*)&bs[(wc * 64 + nj * 16 + lm) * KPAD + lk];
#pragma unroll
    for (int mi = 0; mi < 4; ++mi)
#pragma unroll
      for (int nj = 0; nj < 4; ++nj)
        acc[mi][nj] = __builtin_amdgcn_mfma_f32_16x16x32_bf16(af[mi], bfr[nj], acc[mi][nj], 0, 0, 0);
  };

  fetchR(kbeg);
  if (nt > 1) fetchS(kbeg + BK);
  writeR(0);
  if (nt > 2) fetchR(kbeg + 2 * BK);
  __syncthreads();

  for (int it = 0; it < nt; it += 2) {
    writeS(1);
    if (it + 3 < nt) fetchS(kbeg + (it + 3) * BK);
    computeBuf(&As[0][0], &Bs[0][0]);
    __syncthreads();
    if (it + 2 < nt) writeR(0);
    if (it + 4 < nt) fetchR(kbeg + (it + 4) * BK);
    computeBuf(&As[1][0], &Bs[1][0]);
    __syncthreads();
  }

  const int rbase = m0 + wr * 64;
  const int cbase = n0 + wc * 64;

  if constexpr (MODE == 0) {
#pragma unroll
    for (int mi = 0; mi < 4; ++mi)
#pragma unroll
      for (int r = 0; r < 4; ++r) {
        int grow = rbase + mi * 16 + kg * 4 + r;
#pragma unroll
        for (int nj = 0; nj < 4; ++nj) {
          int gcol = cbase + nj * 16 + lm;
          float t = acc[mi][nj][r] + (bias ? bias[gcol] : 0.f);
          float v = do_relu ? fmaxf(t, 0.f) : t;
          size_t idx = (size_t)grow * N + gcol;
          if constexpr (CBF16) ((unsigned short*)Cv)[idx] = f2bf(v);
          else                 ((float*)Cv)[idx] = v;
        }
      }
  } else if constexpr (MODE == 6) {
#pragma unroll
    for (int mi = 0; mi < 4; ++mi)
#pragma unroll
      for (int r = 0; r < 4; ++r) {
        int grow = rbase + mi * 16 + kg * 4 + r;
#pragma unroll
        for (int nj = 0; nj < 4; ++nj) {
          int gcol = cbase + nj * 16 + lm;
          int grp = gcol >> 10, col = gcol & 1023;
          float t = acc[mi][nj][r] + bias[gcol];
          float v = (grp == 3) ? fmaxf(x1[col] * t, 0.f) : t;
          ((unsigned short*)Cv)[((size_t)grp * M + grow) * 1024 + col] = f2bf(v);
        }
      }
  } else if constexpr (MODE == 5) {
    size_t zofs = (size_t)bz * M;
#pragma unroll
    for (int mi = 0; mi < 4; ++mi)
#pragma unroll
      for (int r = 0; r < 4; ++r) {
        int grow = rbase + mi * 16 + kg * 4 + r;
#pragma unroll
        for (int nj = 0; nj < 4; ++nj) {
          int gcol = cbase + nj * 16 + lm;
          part[(zofs + grow) * N + gcol] = acc[mi][nj][r];
        }
      }
  } else if constexpr (MODE == 7) {
#pragma unroll
    for (int mi = 0; mi < 4; ++mi)
#pragma unroll
      for (int r = 0; r < 4; ++r) {
        int grow = rbase + mi * 16 + kg * 4 + r;
        int h = grow / NNN, n = grow - h * NNN;
        if (n == h) continue;
        long long orow = grow - h - (n > h ? 1 : 0);
#pragma unroll
        for (int nj = 0; nj < 4; ++nj) {
          int gcol = cbase + nj * 16 + lm;
          float v = fmaxf(acc[mi][nj][r] + biasUse[gcol], 0.f);
          ((float*)Cv)[orow * 2048 + cofs + gcol] = v;
        }
      }
  } else if constexpr (MODE == 1) {
#pragma unroll
    for (int mi = 0; mi < 4; ++mi)
#pragma unroll
      for (int r = 0; r < 4; ++r) {
        float s = 0.f;
#pragma unroll
        for (int nj = 0; nj < 4; ++nj) {
          int gcol = cbase + nj * 16 + lm;
          float v = fmaxf(acc[mi][nj][r] + bias[gcol], 0.f);
          s = fmaf(v, x1[gcol], s);
        }
#pragma unroll
        for (int off2 = 1; off2 < 16; off2 <<= 1) s += __shfl_xor(s, off2);
        if (lm == 0) red2[wr * 64 + mi * 16 + kg * 4 + r][wc] = s;
      }
    __syncthreads();
    if (tid < BM) {
      part[(size_t)(m0 + tid) * 8 + bx] = red2[tid][0] + red2[tid][1];
    }
  }
}

// V[p,j] = relu((uh[h,j] + un[n,j]) * vA[p*vstride+j])   (vA,V bf16)
__global__ __launch_bounds__(256) void tmulb_k(const unsigned short* __restrict__ vA,
    int vstride, const float* __restrict__ uh, const float* __restrict__ un,
    unsigned short* __restrict__ V)
{
  int p = blockIdx.x;
  int h = p / NNN, n = p - h * NNN;
  int j = threadIdx.x * 4;
  const float* uhr = uh + (size_t)h * NEC + j;
  const float* unr = un + (size_t)n * NEC + j;
  uint2 w = *(const uint2*)(vA + (size_t)p * vstride + j);
  float v0 = bf2f((unsigned short)(w.x & 0xffff));
  float v1 = bf2f((unsigned short)(w.x >> 16));
  float v2 = bf2f((unsigned short)(w.y & 0xffff));
  float v3 = bf2f((unsigned short)(w.y >> 16));
  float f0 = fmaxf((uhr[0] + unr[0]) * v0, 0.f);
  float f1 = fmaxf((uhr[1] + unr[1]) * v1, 0.f);
  float f2 = fmaxf((uhr[2] + unr[2]) * v2, 0.f);
  float f3 = fmaxf((uhr[3] + unr[3]) * v3, 0.f);
  uint2 o;
  o.x = (unsigned)f2bf(f0) | ((unsigned)f2bf(f1) << 16);
  o.y = (unsigned)f2bf(f2) | ((unsigned)f2bf(f3) << 16);
  *(uint2*)(V + (size_t)p * NEC + j) = o;
}

// ---------------------------------------------------------------------------
// 256-thread unified GEMM (f32 A paths): MODE 0 only now (sp1, uG).
// ---------------------------------------------------------------------------
template<int MODE, int ABF16, int BBF16, int CBF16>
__global__ __launch_bounds__(256) void gemm_mfma(
    const void* __restrict__ Av, const void* __restrict__ Bv, long long ldbBlock,
    void* __restrict__ Cv, int M, int N, int K, int Ks,
    const float* __restrict__ bias, int do_relu,
    const float* __restrict__ x1, const float* __restrict__ x2,
    float* __restrict__ part, int colofs, int swz)
{
  __shared__ unsigned short As[BM * KPAD];
  __shared__ unsigned short Bs[BN * KPAD];

  const float* Af = (const float*)Av;
  const unsigned short* Ab = (const unsigned short*)Av;
  const float* Bf = (const float*)Bv;
  const unsigned short* Bb = (const unsigned short*)Bv;

  const int tid  = threadIdx.x;
  const int lane = tid & 63;
  const int wave = tid >> 6;
  const int wr = wave >> 1, wc = wave & 1;
  const int lm = lane & 15;
  const int kg = lane >> 4;

  int bx = blockIdx.x, by = blockIdx.y, bz = blockIdx.z;
  if (swz == 2) {
    int gy = gridDim.y;
    int ntile = gy * gridDim.z;
    int L = (bz * gy + by) * 8 + bx;
    int r = L & 7, q = L >> 3;
    int tpx = ntile >> 3;
    int tile = r * tpx + (q >> 3);
    bx = q & 7;
    bz = tile / gy;
    by = tile - bz * gy;
  }
  const int m0 = by * BM, n0 = bx * BN;
  const int kbeg = bz * Ks;
  const int kend = min(K, kbeg + Ks);

  f32x4 acc[4][4];
#pragma unroll
  for (int i = 0; i < 4; ++i)
#pragma unroll
    for (int j = 0; j < 4; ++j)
      acc[i][j] = (f32x4){0.f, 0.f, 0.f, 0.f};

  const int bn = tid & 127;
  const int kb = (tid >> 7) * 16;
  const float* bsrc = nullptr; long long bstride = 0;
  if constexpr (!BBF16) {
    int gcol = n0 + bn;
    if (ldbBlock) { bsrc = Bf + (long long)(gcol >> 6) * ldbBlock + (gcol & 63); bstride = 64; }
    else          { bsrc = Bf + gcol; bstride = N; }
  }

  uint4 pa0 = {0,0,0,0}, pa1 = {0,0,0,0};
  uint2 qa0 = {0,0}, qa1 = {0,0}, qa2 = {0,0}, qa3 = {0,0};
  uint4 pb0 = {0,0,0,0}, pb1 = {0,0,0,0};

  auto fetchA = [&](int k0) {
    if constexpr (ABF16) {
      int m = tid >> 1, kh = (tid & 1) * 16;
      int gm = m0 + m;
      pa0 = (uint4){0,0,0,0}; pa1 = (uint4){0,0,0,0};
      if (gm < M) {
        const uint4* s = (const uint4*)(Ab + (size_t)gm * K + k0 + kh);
        pa0 = s[0]; pa1 = s[1];
      }
    } else {
#define LOADA_F32(J, DST) { \
      int m = (tid >> 3) + J * 32; int k = (tid & 7) * 4; \
      int gm = m0 + m, gk = k0 + k; \
      float x0=0.f, x1v=0.f, x2v=0.f, x3=0.f; \
      if (gm < M) { const float* src = Af + (long long)gm * K + gk; \
        if (gk + 3 < K) { float4 v = *(const float4*)src; x0=v.x; x1v=v.y; x2v=v.z; x3=v.w; } \
        else { if (gk < K) x0 = src[0]; if (gk+1 < K) x1v = src[1]; \
               if (gk+2 < K) x2v = src[2]; if (gk+3 < K) x3 = src[3]; } } \
      DST.x = (unsigned)f2bf(x0)  | ((unsigned)f2bf(x1v) << 16); \
      DST.y = (unsigned)f2bf(x2v) | ((unsigned)f2bf(x3)  << 16); }
      LOADA_F32(0, qa0) LOADA_F32(1, qa1) LOADA_F32(2, qa2) LOADA_F32(3, qa3)
#undef LOADA_F32
    }
  };
  auto fetchB = [&](int k0) {
    if constexpr (BBF16) {
      int nrow = tid >> 1, kh = (tid & 1) * 16;
      const uint4* s = (const uint4*)(Bb + (size_t)(n0 + nrow) * K + k0 + kh);
      pb0 = s[0]; pb1 = s[1];
    } else {
#define PACKB(I, DST) { int g0 = k0 + kb + 2*I, g1 = g0 + 1; \
      float a = (g0 < K) ? bsrc[(long long)g0 * bstride] : 0.f; \
      float c = (g1 < K) ? bsrc[(long long)g1 * bstride] : 0.f; \
      DST = (unsigned)f2bf(a) | ((unsigned)f2bf(c) << 16); }
      PACKB(0, pb0.x) PACKB(1, pb0.y) PACKB(2, pb0.z) PACKB(3, pb0.w)
      PACKB(4, pb1.x) PACKB(5, pb1.y) PACKB(6, pb1.z) PACKB(7, pb1.w)
#undef PACKB
    }
  };
  auto stage = [&]() {
    if constexpr (ABF16) {
      int m = tid >> 1, kh = (tid & 1) * 16;
      *(uint4*)&As[m * KPAD + kh]     = pa0;
      *(uint4*)&As[m * KPAD + kh + 8] = pa1;
    } else {
      int m = tid >> 3, k = (tid & 7) * 4;
      *(uint2*)&As[(m      ) * KPAD + k] = qa0;
      *(uint2*)&As[(m +  32) * KPAD + k] = qa1;
      *(uint2*)&As[(m +  64) * KPAD + k] = qa2;
      *(uint2*)&As[(m +  96) * KPAD + k] = qa3;
    }
    if constexpr (BBF16) {
      int nrow = tid >> 1, kh = (tid & 1) * 16;
      *(uint4*)&Bs[nrow * KPAD + kh]     = pb0;
      *(uint4*)&Bs[nrow * KPAD + kh + 8] = pb1;
    } else {
      *(uint4*)&Bs[bn * KPAD + kb]     = pb0;
      *(uint4*)&Bs[bn * KPAD + kb + 8] = pb1;
    }
  };

  fetchA(kbeg); fetchB(kbeg);
  for (int k0 = kbeg; k0 < kend; k0 += BK) {
    stage();
    int kn = k0 + BK;
    if (kn < kend) { fetchA(kn); fetchB(kn); }
    __syncthreads();
    {
      const int lk = kg * 8;
      short8v af[4], bfr[4];
#pragma unroll
      for (int mi = 0; mi < 4; ++mi)
        af[mi] = *(const short8v*)&As[(wr * 64 + mi * 16 + lm) * KPAD + lk];
#pragma unroll
      for (int nj = 0; nj < 4; ++nj)
        bfr[nj] = *(const short8v*)&Bs[(wc * 64 + nj * 16 + lm) * KPAD + lk];
#pragma unroll
      for (int mi = 0; mi < 4; ++mi)
#pragma unroll
        for (int nj = 0; nj < 4; ++nj)
          acc[mi][nj] = __builtin_amdgcn_mfma_f32_16x16x32_bf16(af[mi], bfr[nj], acc[mi][nj], 0, 0, 0);
    }
    __syncthreads();
  }

  const int rbase = m0 + wr * 64;
  const int cbase = n0 + wc * 64;

  if constexpr (MODE == 0) {
#pragma unroll
    for (int mi = 0; mi < 4; ++mi)
#pragma unroll
      for (int r = 0; r < 4; ++r) {
        int grow = rbase + mi * 16 + kg * 4 + r;
        if (grow >= M) continue;
#pragma unroll
        for (int nj = 0; nj < 4; ++nj) {
          int gcol = cbase + nj * 16 + lm;
          float t = acc[mi][nj][r] + (bias ? bias[gcol] : 0.f);
          float v = do_relu ? fmaxf(t, 0.f) : t;
          size_t idx = (size_t)grow * N + gcol;
          if constexpr (CBF16) ((unsigned short*)Cv)[idx] = f2bf(v);
          else                 ((float*)Cv)[idx] = v;
        }
      }
  } else if constexpr (MODE == 5) {
    size_t zofs = (size_t)bz * M;
#pragma unroll
    for (int mi = 0; mi < 4; ++mi)
#pragma unroll
      for (int r = 0; r < 4; ++r) {
        int grow = rbase + mi * 16 + kg * 4 + r;
        if (grow >= M) continue;
#pragma unroll
        for (int nj = 0; nj < 4; ++nj) {
          int gcol = cbase + nj * 16 + lm;
          part[(zofs + grow) * N + gcol] = acc[mi][nj][r];
        }
      }
  }
}

// C[i] = maybe_relu(sum_z P[z*MN+i] + bias[i%N]); optional f32 and bf16 outs
__global__ __launch_bounds__(256) void ksum_k(const float* __restrict__ P,
    const float* __restrict__ bias, int do_relu, float* __restrict__ Cf,
    unsigned short* __restrict__ Cb, int MN, int N, int S)
{
  int i = blockIdx.x * 256 + threadIdx.x;
  if (i < MN) {
    float s = 0.f;
    for (int z = 0; z < S; ++z) s += P[(size_t)z * MN + i];
    if (bias) s += bias[i % N];
    float v = do_relu ? fmaxf(s, 0.f) : s;
    if (Cf) Cf[i] = v;
    if (Cb) Cb[i] = f2bf(v);
  }
}

// group-routing ksum: P is [S][M][NG*1024]; column group g -> Cg[m*1024+col] + bg
__global__ __launch_bounds__(256) void ksumg_k(const float* __restrict__ P,
    const float* __restrict__ b0, const float* __restrict__ b1, const float* __restrict__ b2,
    float* __restrict__ C0, float* __restrict__ C1, float* __restrict__ C2,
    int M, int NG, int S)
{
  int i = blockIdx.x * 256 + threadIdx.x;
  int N = NG << 10;
  int total = M * N;
  if (i < total) {
    int m = i / N, c = i - m * N;
    int g = c >> 10, col = c & 1023;
    float s = 0.f;
    for (int z = 0; z < S; ++z) s += P[(size_t)z * total + i];
    const float* b = g == 0 ? b0 : (g == 1 ? b1 : b2);
    if (b) s += b[col];
    float* C = g == 0 ? C0 : (g == 1 ? C1 : C2);
    C[(size_t)m * 1024 + col] = s;
  }
}

// tw[h,j] = sum_n soft[h,n] * relu(uO[n,j] * V[(h*384+n)*sV + j])  -> bf16
__global__ __launch_bounds__(256) void tw_k(const unsigned short* __restrict__ V, int sV,
    const float* __restrict__ uO, const float* __restrict__ soft,
    unsigned short* __restrict__ tw)
{
  int h = blockIdx.x;
  int j = blockIdx.y * 256 + threadIdx.x;
  const float* srow = soft + h * NNN;
  float s = 0.f;
  for (int n = 0; n < NNN; ++n) {
    float v = bf2f(V[((size_t)h * NNN + n) * sV + j]);
    float t = fmaxf(uO[(size_t)n * NEC + j] * v, 0.f);
    s = fmaf(srow[n], t, s);
  }
  tw[(size_t)h * NEC + j] = f2bf(s);
}

// two[n,j] = sum_h softT[n,h] * relu(uS[h,j] * V[(h*384+n)*sV + j])  -> bf16
__global__ __launch_bounds__(256) void two_k(const unsigned short* __restrict__ V, int sV,
    const float* __restrict__ uS, const float* __restrict__ softT,
    unsigned short* __restrict__ two)
{
  int n = blockIdx.x;
  int j = blockIdx.y * 256 + threadIdx.x;
  const float* srow = softT + n * NHH;
  float s = 0.f;
#pragma unroll 8
  for (int h = 0; h < NHH; ++h) {
    float v = bf2f(V[((size_t)h * NNN + n) * sV + j]);
    float t = fmaxf(uS[(size_t)h * NEC + j] * v, 0.f);
    s = fmaf(srow[h], t, s);
  }
  two[(size_t)n * NEC + j] = f2bf(s);
}

// fused adj-finalize + both softmaxes. grid (NHH+NNN, 64 thr)
__global__ __launch_bounds__(64) void softmax2_k(const float* __restrict__ part,
    const float* __restrict__ badj, float* __restrict__ soft, float* __restrict__ softT)
{
  int b = blockIdx.x, t = threadIdx.x;
  float b0 = badj[0];
  if (b < NHH) {
    __shared__ float buf[NNN];
    int h = b;
    float mx = -1e30f;
    for (int n = t; n < NNN; n += 64) {
      size_t p = (size_t)(h * NNN + n) * 8;
      float s = b0;
#pragma unroll
      for (int c = 0; c < 8; ++c) s += part[p + c];
      buf[n] = s;
      mx = fmaxf(mx, s);
    }
#pragma unroll
    for (int off = 32; off >= 1; off >>= 1) mx = fmaxf(mx, __shfl_xor(mx, off));
    float s = 0.f;
    for (int n = t; n < NNN; n += 64) { float e = expf(buf[n] - mx); buf[n] = e; s += e; }
#pragma unroll
    for (int off = 32; off >= 1; off >>= 1) s += __shfl_xor(s, off);
    float inv = 1.f / s;
    for (int n = t; n < NNN; n += 64) soft[h * NNN + n] = buf[n] * inv;
  } else {
    int n = b - NHH;
    float v = -1e30f;
    if (t < NHH) {
      size_t p = (size_t)(t * NNN + n) * 8;
      v = b0;
#pragma unroll
      for (int c = 0; c < 8; ++c) v += part[p + c];
    }
    float mx = v;
#pragma unroll
    for (int off = 32; off >= 1; off >>= 1) mx = fmaxf(mx, __shfl_xor(mx, off));
    float e = (t < NHH) ? expf(v - mx) : 0.f;
    float s = e;
#pragma unroll
    for (int off = 32; off >= 1; off >>= 1) s += __shfl_xor(s, off);
    if (t < NHH) softT[n * NHH + t] = e / s;
  }
}

// out = LN(x+m)*g+b; optional bf16 mirror
__global__ __launch_bounds__(256) void ln_k(const float* __restrict__ x, const float* __restrict__ m,
    const float* __restrict__ g, const float* __restrict__ b, float* __restrict__ out,
    unsigned short* __restrict__ outb)
{
  int r = blockIdx.x, t = threadIdx.x;
  __shared__ float rs[4], rs2[4];
  const float* xr = x + (size_t)r * NEC;
  const float* mr = m + (size_t)r * NEC;
  float s = 0.f, s2 = 0.f;
  for (int j = t; j < NEC; j += 256) { float v = xr[j] + mr[j]; s += v; s2 = fmaf(v, v, s2); }
#pragma unroll
  for (int off = 32; off >= 1; off >>= 1) { s += __shfl_xor(s, off); s2 += __shfl_xor(s2, off); }
  if ((t & 63) == 0) { rs[t >> 6] = s; rs2[t >> 6] = s2; }
  __syncthreads();
  s = rs[0] + rs[1] + rs[2] + rs[3];
  s2 = rs2[0] + rs2[1] + rs2[2] + rs2[3];
  float mean = s * (1.f / NEC);
  float var = s2 * (1.f / NEC) - mean * mean;
  float rstd = rsqrtf(var + 1e-5f);
  float* o = out + (size_t)r * NEC;
  unsigned short* ob = outb ? outb + (size_t)r * NEC : nullptr;
  for (int j = t; j < NEC; j += 256) {
    float v = xr[j] + mr[j];
    float w = (v - mean) * rstd * g[j] + b[j];
    o[j] = w;
    if (ob) ob[j] = f2bf(w);
  }
}

__global__ __launch_bounds__(64) void gfeat_k(const float* __restrict__ feat3,
                                              float* __restrict__ gfeat)
{
  int ch = blockIdx.x, t = threadIdx.x;
  float s = 0.f;
  for (int i = t; i < 625; i += 64) s += feat3[ch * 625 + i];
#pragma unroll
  for (int off = 32; off >= 1; off >>= 1) s += __shfl_xor(s, off);
  if (t == 0) gfeat[ch] = s * (1.f / 625.f);
}

extern "C" void kernel_launch(void* const* d_in, const int* in_sizes, int n_in,
                              void* d_out, int out_size, void* d_ws, size_t ws_size,
                              hipStream_t stream)
{
  const float* box   = (const float*)d_in[0];
  const float* feat3 = (const float*)d_in[1];
  const float* sp36  = (const float*)d_in[2];
  const float* Wbh1  = (const float*)d_in[3];
  const float* bbh1  = (const float*)d_in[4];
  const float* Wbh2  = (const float*)d_in[5];
  const float* bbh2  = (const float*)d_in[6];
  const float* Wsp1  = (const float*)d_in[7];
  const float* bsp1  = (const float*)d_in[8];
  const float* Wsp2  = (const float*)d_in[9];
  const float* bsp2  = (const float*)d_in[10];
  const float* Wsp3  = (const float*)d_in[11];
  const float* bsp3  = (const float*)d_in[12];
  const float* Wadj  = (const float*)d_in[13];
  const float* badj  = (const float*)d_in[14];
  const float* A1W = (const float*)d_in[15]; const float* A1b = (const float*)d_in[16];
  const float* A2W = (const float*)d_in[17]; const float* A2b = (const float*)d_in[18];
  const float* A3W = (const float*)d_in[19]; const float* A3b = (const float*)d_in[20];
  const float* O1W = (const float*)d_in[21]; const float* O1b = (const float*)d_in[22];
  const float* O2W = (const float*)d_in[23]; const float* O2b = (const float*)d_in[24];
  const float* O3W = (const float*)d_in[25]; const float* O3b = (const float*)d_in[26];
  const float* S1W = (const float*)d_in[27]; const float* S1b = (const float*)d_in[28];
  const float* S2W = (const float*)d_in[29]; const float* S2b = (const float*)d_in[30];
  const float* S3W = (const float*)d_in[31]; const float* S3b = (const float*)d_in[32];
  const float* G1W = (const float*)d_in[33]; const float* G1b = (const float*)d_in[34];
  const float* G2W = (const float*)d_in[35]; const float* G2b = (const float*)d_in[36];
  const float* G3W = (const float*)d_in[37]; const float* G3b = (const float*)d_in[38];
  const float* gln_h = (const float*)d_in[39]; const float* bln_h = (const float*)d_in[40];
  const float* gln_o = (const float*)d_in[41]; const float* bln_o = (const float*)d_in[42];
  (void)in_sizes; (void)n_in; (void)out_size; (void)ws_size;

  // ---- workspace carve ----
  char* base = (char*)d_ws;
  unsigned short* VQ  = (unsigned short*)base;            // 4 x [NP][1024] bf16 (151 MB total)
  unsigned short* VAq = VQ + (size_t)0 * NP * 1024;       // vA
  unsigned short* VOq = VQ + (size_t)1 * NP * 1024;       // vO
  unsigned short* VSq = VQ + (size_t)2 * NP * 1024;       // vS
  unsigned short* VGq = VQ + (size_t)3 * NP * 1024;       // t_glob
  float* partialV4    = (float*)base;                     // early split-K partials (box, node MLP)
  unsigned short* Vb  = (unsigned short*)(base + (size_t)NP * 4096 * 2);  // [NP][1024] bf16
  float* partialVb    = (float*)Vb;
  unsigned short* s1  = Vb;                               // sp stage 1 alias
  unsigned short* s2  = Vb + (size_t)NP * 128;            // sp stage 2 alias
  unsigned short* SPb = Vb + (size_t)NP * 1024;           // [NP][1024] bf16
  float* f = (float*)(SPb + (size_t)NP * 1024);
  size_t off = 0;
  auto alloc = [&](size_t n) { float* p = f + off; off += n; return p; };
  float* node1 = alloc(384 * NEC);
  float* node  = alloc(384 * NEC);
  float* hnode1= alloc(128 * NEC);
  float* node2 = alloc(384 * NEC);
  float* uhA   = alloc(384 * NEC);
  float* unA   = alloc(384 * NEC);
  float* uO    = alloc(384 * NEC);
  float* uS    = alloc(128 * NEC);
  float* uh2   = alloc(128 * NEC);
  float* un2   = alloc(384 * NEC);
  float* uG    = alloc(NEC);
  float* gfeat = alloc(256);
  float* b3A = alloc(NEC); float* b3O = alloc(NEC); float* b3S = alloc(NEC); float* b3G = alloc(NEC);
  float* bias4 = alloc(4096);
  float* part  = alloc((size_t)NP * 8);
  float* adj   = alloc(NP);
  float* soft  = alloc(NP);
  float* softT = alloc(NP);
  float* m_h   = alloc(128 * NEC);      // padded to 128 rows (ksum writes full pad)
  float* m_o   = alloc(384 * NEC);
  // bf16 converted operands (persist whole call)
  unsigned short* wb = (unsigned short*)(f + off);
  size_t wo = 0;
  auto walloc = [&](size_t n) { unsigned short* p = wb + wo; wo += n; return p; };
  unsigned short* W4b   = walloc((size_t)4 * MB1);        // [A2|O2|S2|G2]^T [4096][1024]
  unsigned short* A3Wb  = walloc((size_t)MB1);
  unsigned short* G3Wb  = walloc((size_t)MB1);
  unsigned short* O3Wb  = walloc((size_t)MB1);
  unsigned short* S3Wb  = walloc((size_t)MB1);
  unsigned short* Wsp3b = walloc((size_t)NEC * 256);
  unsigned short* Wsp2b = walloc((size_t)256 * 128);
  unsigned short* Wbh1b = walloc((size_t)NEC * 12544);
  unsigned short* Wbh2b = walloc((size_t)MB1);
  unsigned short* U1b   = walloc((size_t)3 * MB1);        // [W1h|W1n|O1W]^T [3072][1024]
  unsigned short* U2b   = walloc((size_t)2 * MB1);        // [S1W|W1h]^T [2048][1024]
  unsigned short* boxb  = walloc((size_t)384 * 12544);
  unsigned short* nodeb = walloc((size_t)384 * NEC);
  unsigned short* node1b= walloc((size_t)384 * NEC);
  unsigned short* hnode1b = walloc((size_t)128 * NEC);
  unsigned short* node2b  = walloc((size_t)384 * NEC);
  unsigned short* twbb  = walloc((size_t)128 * NEC);      // tw bf16, padded rows
  unsigned short* twobb = walloc((size_t)384 * NEC);      // two bf16

  auto convw = [&](const float* W, unsigned short* out, int inK, int outK, int N,
                   int blocked, int koff) {
    dim3 g(outK / 64, N / 64);
    hipLaunchKernelGGL(convw_k, g, dim3(256), 0, stream, W, out, inK, outK, N, blocked, koff);
  };

  // ---- one-time conversions: 14 x [1024][1024] jobs in ONE launch ----
  {
    CJobs J;
    J.src[0]=A2W;  J.dst[0]=W4b+0*MB1;   J.inK[0]=1024; J.koff[0]=0;    J.blocked[0]=1;
    J.src[1]=O2W;  J.dst[1]=W4b+1*MB1;   J.inK[1]=1024; J.koff[1]=0;    J.blocked[1]=1;
    J.src[2]=S2W;  J.dst[2]=W4b+2*MB1;   J.inK[2]=1024; J.koff[2]=0;    J.blocked[2]=1;
    J.src[3]=G2W;  J.dst[3]=W4b+3*MB1;   J.inK[3]=1024; J.koff[3]=0;    J.blocked[3]=1;
    J.src[4]=A1W;  J.dst[4]=U1b+0*MB1;   J.inK[4]=2048; J.koff[4]=0;    J.blocked[4]=1;
    J.src[5]=A1W;  J.dst[5]=U1b+1*MB1;   J.inK[5]=2048; J.koff[5]=1024; J.blocked[5]=1;
    J.src[6]=O1W;  J.dst[6]=U1b+2*MB1;   J.inK[6]=1024; J.koff[6]=0;    J.blocked[6]=1;
    J.src[7]=S1W;  J.dst[7]=U2b+0*MB1;   J.inK[7]=1024; J.koff[7]=0;    J.blocked[7]=1;
    J.src[8]=A1W;  J.dst[8]=U2b+1*MB1;   J.inK[8]=2048; J.koff[8]=0;    J.blocked[8]=1;
    J.src[9]=A3W;  J.dst[9]=A3Wb;        J.inK[9]=1024; J.koff[9]=0;    J.blocked[9]=0;
    J.src[10]=G3W; J.dst[10]=G3Wb;       J.inK[10]=1024;J.koff[10]=0;   J.blocked[10]=0;
    J.src[11]=Wbh2;J.dst[11]=Wbh2b;      J.inK[11]=1024;J.koff[11]=0;   J.blocked[11]=0;
    J.src[12]=O3W; J.dst[12]=O3Wb;       J.inK[12]=1024;J.koff[12]=0;   J.blocked[12]=0;
    J.src[13]=S3W; J.dst[13]=S3Wb;       J.inK[13]=1024;J.koff[13]=0;   J.blocked[13]=0;
    hipLaunchKernelGGL(convjobs_k, dim3(16, 16, 14), dim3(256), 0, stream, J);
  }
  convw(Wsp3, Wsp3b, 256, 256, NEC, 0, 0);
  convw(Wsp2, Wsp2b, 128, 128, 256, 0, 0);
  convw(Wbh1, Wbh1b, 12544, 12544, NEC, 0, 0);
  cvt_k<<<(384 * 12544 / 4 + 255) / 256, 256, 0, stream>>>(box, boxb, 384 * 12544);

  gfeat_k<<<256, 64, 0, stream>>>(feat3, gfeat);
  {
    Ptr4 P; P.s[0]=A3b; P.s[1]=O3b; P.s[2]=S3b; P.s[3]=G3b;
    P.d[0]=b3A; P.d[1]=b3O; P.d[2]=b3S; P.d[3]=b3G;
    hipLaunchKernelGGL(b3sum4_k, dim3(4, 4), dim3(256), 0, stream, P);
  }
  biascat4_k<<<16, 256, 0, stream>>>(A2b, O2b, S2b, G2b, bias4);

  // ---- node MLP (partials in dead VQ region; bf16 outs fused into ksum) ----
  {
    dim3 grid(8, 3, 16);                         // box: S=16, Ks=832
    hipLaunchKernelGGL((gemm_db<5, 0>), grid, dim3(256), 0, stream,
                       boxb, 12544, Wbh1b, 12544, nullptr, 384, NEC, 12544, 832,
                       nullptr, 0, nullptr, nullptr, partialV4, 0, 2);
    hipLaunchKernelGGL(ksum_k, dim3((384 * NEC + 255) / 256), dim3(256), 0, stream,
                       partialV4, bbh1, 1, (float*)nullptr, node1b, 384 * NEC, NEC, 16);
  }
  {
    dim3 grid(8, 3, 8);                          // Ks=128, 4 tiles/slice
    hipLaunchKernelGGL((gemm_db<5, 0>), grid, dim3(256), 0, stream,
                       node1b, NEC, Wbh2b, NEC, nullptr, 384, NEC, NEC, 128,
                       nullptr, 0, nullptr, nullptr, partialV4, 0, 2);
    hipLaunchKernelGGL(ksum_k, dim3((384 * NEC + 255) / 256), dim3(256), 0, stream,
                       partialV4, bbh2, 1, node, nodeb, 384 * NEC, NEC, 8);
  }

  // ---- spatial MLP -> SPb (s1/s2 alias Vb) ----
  {
    dim3 g1(1, NP / BM);
    hipLaunchKernelGGL((gemm_mfma<0, 0, 0, 1>), g1, dim3(256), 0, stream,
                       sp36, Wsp1, 0LL, s1, NP, 128, 36, 36, bsp1, 1, nullptr, nullptr, nullptr, 0, 0);
    dim3 g2(2, NP / BM);
    hipLaunchKernelGGL((gemm_db<0, 1>), g2, dim3(256), 0, stream,
                       s1, 128, Wsp2b, 128, s2, NP, 256, 128, 128, bsp2, 1,
                       nullptr, nullptr, nullptr, 0, 0);
    dim3 g3(8, NP / BM);
    hipLaunchKernelGGL((gemm_db<0, 1>), g3, dim3(256), 0, stream,
                       s2, 256, Wsp3b, 256, SPb, NP, NEC, 256, 256, bsp3, 1,
                       nullptr, nullptr, nullptr, 0, 1);
  }

  // ---- uG (tiny, must precede FUSED4) ----
  {
    dim3 g1(8, 1);
    hipLaunchKernelGGL((gemm_mfma<0, 0, 0, 0>), g1, dim3(256), 0, stream,
                       gfeat, G1W, 256LL * 64, uG, 1, NEC, 256, 256, G1b, 0,
                       nullptr, nullptr, nullptr, 0, 0);
  }

  // ---- FUSED4: {vA,vO,vS,tG} = SPb @ [A2|O2|S2|G2] -> 4 contiguous buffers ----
  {
    dim3 grid(32, NP / BM);
    hipLaunchKernelGGL((gemm_db<6, 1>), grid, dim3(256), 0, stream,
                       SPb, NEC, W4b, NEC, VQ, NP, 4096, NEC, NEC,
                       bias4, 0, uG, nullptr, nullptr, 0, 3);
  }

  // ---- U1: [uhA|unA|uO] = node @ [W1h|W1n|O1W] ----
  {
    dim3 grid(24, 3, 8);                         // Ks=128
    hipLaunchKernelGGL((gemm_db<5, 0>), grid, dim3(256), 0, stream,
                       nodeb, NEC, U1b, NEC, nullptr, 384, 3072, NEC, 128,
                       nullptr, 0, nullptr, nullptr, partialVb, 0, 0);
    int total = 384 * 3072;
    hipLaunchKernelGGL(ksumg_k, dim3((total + 255) / 256), dim3(256), 0, stream,
                       partialVb, A1b, (const float*)nullptr, O1b, uhA, unA, uO, 384, 3, 8);
  }

  // ---- adjacency head ----
  tmulb_k<<<NP, 256, 0, stream>>>(VAq, 1024, uhA, unA, Vb);      // V = relu((uh+un)*vA)
  {
    dim3 g(8, NP / BM);
    hipLaunchKernelGGL((gemm_db<1, 0>), g, dim3(256), 0, stream,
                       Vb, NEC, A3Wb, NEC, nullptr, NP, NEC, NEC, NEC,
                       b3A, 1, Wadj, nullptr, part, 0, 1);
  }
  softmax2_k<<<NHH + NNN, 64, 0, stream>>>(part, badj, soft, softT);

  // ---- m_h (O head): vO contiguous; tw -> bf16 -> bf16 GEMM ----
  tw_k<<<dim3(NHH, 4), 256, 0, stream>>>(VOq, 1024, uO, soft, twbb);
  {
    dim3 grid(8, 1, 8);                          // M padded to 128; Ks=128; swz=2 (gy*gz=8)
    hipLaunchKernelGGL((gemm_db<5, 0>), grid, dim3(256), 0, stream,
                       twbb, NEC, O3Wb, NEC, nullptr, 128, NEC, NEC, 128,
                       nullptr, 0, nullptr, nullptr, partialVb, 0, 2);
    hipLaunchKernelGGL(ksum_k, dim3((128 * NEC + 255) / 256), dim3(256), 0, stream,
                       partialVb, b3O, 1, m_h, (unsigned short*)nullptr, 128 * NEC, NEC, 8);
  }
  ln_k<<<NHH, 256, 0, stream>>>(node, m_h, gln_h, bln_h, hnode1, hnode1b);

  // ---- U2: [uS|uh2] = hnode1 @ [S1W|W1h] ----
  {
    dim3 grid(16, 1, 8);
    hipLaunchKernelGGL((gemm_db<5, 0>), grid, dim3(256), 0, stream,
                       hnode1b, NEC, U2b, NEC, nullptr, 128, 2048, NEC, 128,
                       nullptr, 0, nullptr, nullptr, partialVb, 0, 0);
    int total = 128 * 2048;
    hipLaunchKernelGGL(ksumg_k, dim3((total + 255) / 256), dim3(256), 0, stream,
                       partialVb, S1b, A1b, (const float*)nullptr, uS, uh2, (float*)nullptr, 128, 2, 8);
  }

  // ---- m_o (S head): vS contiguous; two -> bf16 -> bf16 GEMM ----
  two_k<<<dim3(NNN, 4), 256, 0, stream>>>(VSq, 1024, uS, softT, twobb);
  {
    dim3 grid(8, 3, 8);                          // Ks=128; swz=2 (gy*gz=24)
    hipLaunchKernelGGL((gemm_db<5, 0>), grid, dim3(256), 0, stream,
                       twobb, NEC, S3Wb, NEC, nullptr, 384, NEC, NEC, 128,
                       nullptr, 0, nullptr, nullptr, partialVb, 0, 2);
    hipLaunchKernelGGL(ksum_k, dim3((384 * NEC + 255) / 256), dim3(256), 0, stream,
                       partialVb, b3S, 1, m_o, (unsigned short*)nullptr, 384 * NEC, NEC, 8);
  }
  ln_k<<<NNN, 256, 0, stream>>>(node, m_o, gln_o, bln_o, node2, node2b);

  // ---- un2 = node2 @ W1n ----
  {
    dim3 grid(8, 3, 8);
    hipLaunchKernelGGL((gemm_db<5, 0>), grid, dim3(256), 0, stream,
                       node2b, NEC, U1b + 1 * MB1, NEC, nullptr, 384, NEC, NEC, 128,
                       nullptr, 0, nullptr, nullptr, partialVb, 0, 2);
    hipLaunchKernelGGL(ksum_k, dim3((384 * NEC + 255) / 256), dim3(256), 0, stream,
                       partialVb, (const float*)nullptr, 0, un2, (unsigned short*)nullptr, 384 * NEC, NEC, 8);
  }

  // ---- f_pair V (reuses contiguous vA) ----
  tmulb_k<<<NP, 256, 0, stream>>>(VAq, 1024, uh2, un2, Vb);

  // ---- merged output GEMM: f_pair (bx<8) + f_glob (bx>=8, contiguous tG) ----
  {
    dim3 g(16, NP / BM);
    hipLaunchKernelGGL((gemm_db<7, 0>), g, dim3(256), 0, stream,
                       Vb, NEC, A3Wb, NEC, (float*)d_out, NP, NEC, NEC, NEC,
                       b3A, 1, (const float*)VGq, (const float*)G3Wb,
                       b3G, 0, 3);
  }
}